// Round 1
// baseline (386.004 us; speedup 1.0000x reference)
//
#include <hip/hip_runtime.h>
#include <stdint.h>

typedef __bf16 bf16x8 __attribute__((ext_vector_type(8)));
typedef float f32x4 __attribute__((ext_vector_type(4)));

__device__ __forceinline__ unsigned short f2bf(float f) {
  unsigned u = __builtin_bit_cast(unsigned, f);
  u = (u + 0x7fffu + ((u >> 16) & 1u)) >> 16;
  return (unsigned short)u;
}

__device__ __forceinline__ void gload_lds16(const unsigned short* g, unsigned short* l) {
  __builtin_amdgcn_global_load_lds(
      (__attribute__((address_space(1))) unsigned int*)g,
      (__attribute__((address_space(3))) unsigned int*)l, 16, 0, 0);
}

__device__ __forceinline__ void store_val(float* p, float v) { *p = v; }
__device__ __forceinline__ void store_val(unsigned short* p, float v) { *p = f2bf(v); }

// ---------------- fp32 -> bf16 convert ----------------
__global__ __launch_bounds__(256) void f2bf_kernel(const float* __restrict__ in,
                                                   unsigned short* __restrict__ out, int n) {
  int stride = gridDim.x * blockDim.x * 4;
  for (int i = (blockIdx.x * blockDim.x + threadIdx.x) * 4; i < n; i += stride) {
    float4 v = *(const float4*)(in + i);
    ushort4 o;
    o.x = f2bf(v.x); o.y = f2bf(v.y); o.z = f2bf(v.z); o.w = f2bf(v.w);
    *(ushort4*)(out + i) = o;
  }
}

// ---------------- transpose fp32 [R][C] -> bf16 [C][R] ----------------
__global__ __launch_bounds__(256) void transpose_f2bf(const float* __restrict__ in,
                                                      unsigned short* __restrict__ out,
                                                      int R, int Ccols) {
  __shared__ unsigned short t[64][65];
  int r0 = blockIdx.y * 64, c0 = blockIdx.x * 64;
  int tid = threadIdx.x;
#pragma unroll
  for (int rep = 0; rep < 16; rep++) {
    int idx = rep * 256 + tid;
    int rr = idx >> 6, cc = idx & 63;
    t[rr][cc] = f2bf(in[(size_t)(r0 + rr) * Ccols + c0 + cc]);
  }
  __syncthreads();
#pragma unroll
  for (int rep = 0; rep < 16; rep++) {
    int idx = rep * 256 + tid;
    int cc = idx >> 6, rr = idx & 63;
    out[(size_t)(c0 + cc) * R + r0 + rr] = t[rr][cc];
  }
}

// ---------------- build V^T per head: vt[bh][d][t] from qkv ----------------
__global__ __launch_bounds__(256) void make_vt(const unsigned short* __restrict__ qkv,
                                               unsigned short* __restrict__ vt) {
  __shared__ unsigned short t[64][65];
  int bh = blockIdx.x;
  int b = bh >> 4, h = bh & 15;
  int t0 = blockIdx.y * 64;
  int tid = threadIdx.x;
#pragma unroll
  for (int rep = 0; rep < 16; rep++) {
    int idx = rep * 256 + tid;
    int tt = idx >> 6, dd = idx & 63;
    t[tt][dd] = qkv[(size_t)(b * 2048 + t0 + tt) * 3072 + 2048 + h * 64 + dd];
  }
  __syncthreads();
#pragma unroll
  for (int rep = 0; rep < 16; rep++) {
    int idx = rep * 256 + tid;
    int dd = idx >> 6, tt = idx & 63;
    vt[(size_t)bh * 131072 + (size_t)dd * 2048 + t0 + tt] = t[tt][dd];
  }
}

// ---------------- bf16 GEMM: C[M][N] = A[M][K] * Bt[N][K]^T ----------------
// 128x128 tile, 4 waves, 16x16x32 bf16 MFMA, global_load_lds staging,
// XOR-swizzled K-chunks (swizzle applied to global source; LDS dest linear).
template <typename OutT>
__global__ __launch_bounds__(256) void gemm_bt(const unsigned short* __restrict__ A,
                                               const unsigned short* __restrict__ Bt,
                                               OutT* __restrict__ C, int M, int N, int K) {
  __shared__ unsigned short a_lds[128 * 32];
  __shared__ unsigned short b_lds[128 * 32];
  int tid = threadIdx.x;
  int w = tid >> 6, l = tid & 63;
  int wr = w >> 1, wc = w & 1;
  int lr = l & 15, lg = l >> 4;
  int m0 = blockIdx.y * 128, n0 = blockIdx.x * 128;

  // staging map: thread t covers lds bytes t*16 (row=t/4, chunk=t&3 of 8 elems).
  // swizzle: lds[r][c*8+j] holds A[r][(c^(r&3))*8+j]
  int r = tid >> 2;
  int scol = ((tid & 3) ^ (r & 3)) * 8;
  const unsigned short* gA = A + (size_t)(m0 + r) * K + scol;
  const unsigned short* gA2 = gA + (size_t)64 * K;
  const unsigned short* gB = Bt + (size_t)(n0 + r) * K + scol;
  const unsigned short* gB2 = gB + (size_t)64 * K;
  unsigned short* la = &a_lds[w * 512];
  unsigned short* la2 = &a_lds[2048 + w * 512];
  unsigned short* lb = &b_lds[w * 512];
  unsigned short* lb2 = &b_lds[2048 + w * 512];

  // fragment read offset with matching inverse swizzle (row&3 == lr&3)
  int xoff = (lg ^ (lr & 3)) * 8;

  f32x4 acc[4][4] = {};

  for (int k0 = 0; k0 < K; k0 += 32) {
    gload_lds16(gA + k0, la);
    gload_lds16(gA2 + k0, la2);
    gload_lds16(gB + k0, lb);
    gload_lds16(gB2 + k0, lb2);
    __syncthreads();
    bf16x8 af[4], bfr[4];
#pragma unroll
    for (int m = 0; m < 4; m++)
      af[m] = *(const bf16x8*)&a_lds[(wr * 64 + m * 16 + lr) * 32 + xoff];
#pragma unroll
    for (int n = 0; n < 4; n++)
      bfr[n] = *(const bf16x8*)&b_lds[(wc * 64 + n * 16 + lr) * 32 + xoff];
#pragma unroll
    for (int m = 0; m < 4; m++)
#pragma unroll
      for (int n = 0; n < 4; n++)
        acc[m][n] = __builtin_amdgcn_mfma_f32_16x16x32_bf16(af[m], bfr[n], acc[m][n], 0, 0, 0);
    __syncthreads();
  }

#pragma unroll
  for (int m = 0; m < 4; m++)
#pragma unroll
    for (int n = 0; n < 4; n++)
#pragma unroll
      for (int i = 0; i < 4; i++) {
        size_t row = (size_t)(m0 + wr * 64 + m * 16 + lg * 4 + i);
        size_t col = (size_t)(n0 + wc * 64 + n * 16 + lr);
        store_val(&C[row * N + col], acc[m][n][i]);
      }
}

// ---------------- flash attention, causal ----------------
// 1 wave per (bh, 16-row q strip). K/V direct from global (L2-resident per head).
__global__ __launch_bounds__(64) void attn_kernel(const unsigned short* __restrict__ qkv,
                                                  const unsigned short* __restrict__ vt,
                                                  unsigned short* __restrict__ y) {
  __shared__ unsigned short p_lds[16 * 64];
  int l = threadIdx.x;
  int lr = l & 15, lg = l >> 4;
  int bh = blockIdx.x;
  int b = bh >> 4, h = bh & 15;
  int q0 = blockIdx.y * 16;

  const unsigned short* qp = qkv + (size_t)(b * 2048 + q0 + lr) * 3072 + h * 64 + lg * 8;
  bf16x8 aQ0 = *(const bf16x8*)qp;
  bf16x8 aQ1 = *(const bf16x8*)(qp + 32);

  const unsigned short* kbgl = qkv + (size_t)(b * 2048) * 3072 + 1024 + h * 64 + lg * 8;
  const unsigned short* vbgl = vt + (size_t)bh * 131072 + (size_t)lr * 2048 + lg * 8;

  f32x4 O[4] = {};
  float mrow[4] = {-1e30f, -1e30f, -1e30f, -1e30f};
  float lsum[4] = {0.f, 0.f, 0.f, 0.f};

  int nb = (q0 >> 6) + 1;
  for (int kb = 0; kb < nb; kb++) {
    int kbase = kb * 64;
    bool diag = (kb == nb - 1);
    f32x4 s[4];
#pragma unroll
    for (int n = 0; n < 4; n++) {
      const unsigned short* kp = kbgl + (size_t)(kbase + n * 16 + lr) * 3072;
      bf16x8 kf0 = *(const bf16x8*)kp;
      bf16x8 kf1 = *(const bf16x8*)(kp + 32);
      f32x4 z = {};
      z = __builtin_amdgcn_mfma_f32_16x16x32_bf16(aQ0, kf0, z, 0, 0, 0);
      z = __builtin_amdgcn_mfma_f32_16x16x32_bf16(aQ1, kf1, z, 0, 0, 0);
      s[n] = z;
    }
    float tmax[4] = {-1e30f, -1e30f, -1e30f, -1e30f};
#pragma unroll
    for (int n = 0; n < 4; n++)
#pragma unroll
      for (int i = 0; i < 4; i++) {
        float v = s[n][i] * 0.125f;
        if (diag && (kbase + n * 16 + lr > q0 + lg * 4 + i)) v = -1e30f;
        s[n][i] = v;
        tmax[i] = fmaxf(tmax[i], v);
      }
#pragma unroll
    for (int i = 0; i < 4; i++) {
      float t = tmax[i];
      t = fmaxf(t, __shfl_xor(t, 1));
      t = fmaxf(t, __shfl_xor(t, 2));
      t = fmaxf(t, __shfl_xor(t, 4));
      t = fmaxf(t, __shfl_xor(t, 8));
      tmax[i] = t;
    }
    float fac[4], psum[4] = {0.f, 0.f, 0.f, 0.f};
#pragma unroll
    for (int i = 0; i < 4; i++) {
      float mnew = fmaxf(mrow[i], tmax[i]);
      fac[i] = expf(mrow[i] - mnew);
      mrow[i] = mnew;
    }
#pragma unroll
    for (int n = 0; n < 4; n++)
#pragma unroll
      for (int i = 0; i < 4; i++) {
        float p = expf(s[n][i] - mrow[i]);
        s[n][i] = p;
        psum[i] += p;
      }
#pragma unroll
    for (int i = 0; i < 4; i++) {
      float t = psum[i];
      t += __shfl_xor(t, 1);
      t += __shfl_xor(t, 2);
      t += __shfl_xor(t, 4);
      t += __shfl_xor(t, 8);
      lsum[i] = lsum[i] * fac[i] + t;
    }
#pragma unroll
    for (int n2 = 0; n2 < 4; n2++)
#pragma unroll
      for (int i = 0; i < 4; i++)
        O[n2][i] *= fac[i];
    // P -> LDS (XOR-swizzled to kill ds_read_b128 bank conflicts)
#pragma unroll
    for (int n = 0; n < 4; n++)
#pragma unroll
      for (int i = 0; i < 4; i++) {
        int rw = lg * 4 + i;
        int cw = n * 16 + lr;
        p_lds[rw * 64 + (cw ^ ((rw & 7) * 8))] = f2bf(s[n][i]);
      }
    __syncthreads();
    bf16x8 aP0 = *(const bf16x8*)&p_lds[lr * 64 + ((lg * 8) ^ ((lr & 7) * 8))];
    bf16x8 aP1 = *(const bf16x8*)&p_lds[lr * 64 + ((32 + lg * 8) ^ ((lr & 7) * 8))];
#pragma unroll
    for (int n2 = 0; n2 < 4; n2++) {
      const unsigned short* vp = vbgl + (size_t)(n2 * 16) * 2048 + kbase;
      bf16x8 v0 = *(const bf16x8*)vp;
      bf16x8 v1 = *(const bf16x8*)(vp + 32);
      O[n2] = __builtin_amdgcn_mfma_f32_16x16x32_bf16(aP0, v0, O[n2], 0, 0, 0);
      O[n2] = __builtin_amdgcn_mfma_f32_16x16x32_bf16(aP1, v1, O[n2], 0, 0, 0);
    }
    __syncthreads();
  }
#pragma unroll
  for (int n2 = 0; n2 < 4; n2++)
#pragma unroll
    for (int i = 0; i < 4; i++) {
      float v = O[n2][i] / lsum[i];
      y[(size_t)(b * 2048 + q0 + lg * 4 + i) * 1024 + h * 64 + n2 * 16 + lr] = f2bf(v);
    }
}

extern "C" void kernel_launch(void* const* d_in, const int* in_sizes, int n_in,
                              void* d_out, int out_size, void* d_ws, size_t ws_size,
                              hipStream_t stream) {
  const float* x = (const float*)d_in[0];
  const float* Wa = (const float*)d_in[1];
  const float* Wp = (const float*)d_in[2];
  float* out = (float*)d_out;

  char* ws = (char*)d_ws;
  size_t off = 0;
  unsigned short* xb = (unsigned short*)(ws + off);   off += (size_t)8192 * 1024 * 2;   // 16 MB
  unsigned short* Wta = (unsigned short*)(ws + off);  off += (size_t)3072 * 1024 * 2;   // 6 MB
  unsigned short* Wtp = (unsigned short*)(ws + off);  off += (size_t)1024 * 1024 * 2;   // 2 MB
  unsigned short* qkvb = (unsigned short*)(ws + off); off += (size_t)8192 * 3072 * 2;   // 48 MB
  unsigned short* vtb = (unsigned short*)(ws + off);  off += (size_t)64 * 64 * 2048 * 2; // 16 MB
  unsigned short* yb = (unsigned short*)(ws + off);   off += (size_t)8192 * 1024 * 2;   // 16 MB

  f2bf_kernel<<<2048, 256, 0, stream>>>(x, xb, 8192 * 1024);
  transpose_f2bf<<<dim3(48, 16), 256, 0, stream>>>(Wa, Wta, 1024, 3072);
  transpose_f2bf<<<dim3(16, 16), 256, 0, stream>>>(Wp, Wtp, 1024, 1024);
  gemm_bt<unsigned short><<<dim3(24, 64), 256, 0, stream>>>(xb, Wta, qkvb, 8192, 3072, 1024);
  make_vt<<<dim3(64, 32), 256, 0, stream>>>(qkvb, vtb);
  attn_kernel<<<dim3(64, 128), 64, 0, stream>>>(qkvb, vtb, yb);
  gemm_bt<float><<<dim3(8, 64), 256, 0, stream>>>(yb, Wtp, out, 8192, 1024, 1024);
}

// Round 2
// 381.418 us; speedup vs baseline: 1.0120x; 1.0120x over previous
//
#include <hip/hip_runtime.h>
#include <stdint.h>

typedef __bf16 bf16x8 __attribute__((ext_vector_type(8)));
typedef float f32x4 __attribute__((ext_vector_type(4)));

__device__ __forceinline__ unsigned short f2bf(float f) {
  unsigned u = __builtin_bit_cast(unsigned, f);
  u = (u + 0x7fffu + ((u >> 16) & 1u)) >> 16;
  return (unsigned short)u;
}

__device__ __forceinline__ unsigned cvt_pk_bf16(float a, float b) {
  unsigned r;
  asm("v_cvt_pk_bf16_f32 %0, %1, %2" : "=v"(r) : "v"(a), "v"(b));
  return r;
}

__device__ __forceinline__ void gload_lds16(const unsigned short* g, unsigned short* l) {
  __builtin_amdgcn_global_load_lds(
      (__attribute__((address_space(1))) unsigned int*)g,
      (__attribute__((address_space(3))) unsigned int*)l, 16, 0, 0);
}

__device__ __forceinline__ void store_val(float* p, float v) { *p = v; }
__device__ __forceinline__ void store_val(unsigned short* p, float v) { *p = f2bf(v); }

// ---------------- fp32 -> bf16 convert ----------------
__global__ __launch_bounds__(256) void f2bf_kernel(const float* __restrict__ in,
                                                   unsigned short* __restrict__ out, int n) {
  int stride = gridDim.x * blockDim.x * 4;
  for (int i = (blockIdx.x * blockDim.x + threadIdx.x) * 4; i < n; i += stride) {
    float4 v = *(const float4*)(in + i);
    ushort4 o;
    o.x = f2bf(v.x); o.y = f2bf(v.y); o.z = f2bf(v.z); o.w = f2bf(v.w);
    *(ushort4*)(out + i) = o;
  }
}

// ---------------- transpose fp32 [R][C] -> bf16 [C][R] ----------------
__global__ __launch_bounds__(256) void transpose_f2bf(const float* __restrict__ in,
                                                      unsigned short* __restrict__ out,
                                                      int R, int Ccols) {
  __shared__ unsigned short t[64][65];
  int r0 = blockIdx.y * 64, c0 = blockIdx.x * 64;
  int tid = threadIdx.x;
#pragma unroll
  for (int rep = 0; rep < 16; rep++) {
    int idx = rep * 256 + tid;
    int rr = idx >> 6, cc = idx & 63;
    t[rr][cc] = f2bf(in[(size_t)(r0 + rr) * Ccols + c0 + cc]);
  }
  __syncthreads();
#pragma unroll
  for (int rep = 0; rep < 16; rep++) {
    int idx = rep * 256 + tid;
    int cc = idx >> 6, rr = idx & 63;
    out[(size_t)(c0 + cc) * R + r0 + rr] = t[rr][cc];
  }
}

// ---------------- build V^T per head: vt[bh][d][t] from qkv ----------------
__global__ __launch_bounds__(256) void make_vt(const unsigned short* __restrict__ qkv,
                                               unsigned short* __restrict__ vt) {
  __shared__ unsigned short t[64][65];
  int bh = blockIdx.x;
  int b = bh >> 4, h = bh & 15;
  int t0 = blockIdx.y * 64;
  int tid = threadIdx.x;
#pragma unroll
  for (int rep = 0; rep < 16; rep++) {
    int idx = rep * 256 + tid;
    int tt = idx >> 6, dd = idx & 63;
    t[tt][dd] = qkv[(size_t)(b * 2048 + t0 + tt) * 3072 + 2048 + h * 64 + dd];
  }
  __syncthreads();
#pragma unroll
  for (int rep = 0; rep < 16; rep++) {
    int idx = rep * 256 + tid;
    int dd = idx >> 6, tt = idx & 63;
    vt[(size_t)bh * 131072 + (size_t)dd * 2048 + t0 + tt] = t[tt][dd];
  }
}

// ---------------- bf16 GEMM: C[M][N] = A[M][K] * Bt[N][K]^T ----------------
template <typename OutT>
__global__ __launch_bounds__(256) void gemm_bt(const unsigned short* __restrict__ A,
                                               const unsigned short* __restrict__ Bt,
                                               OutT* __restrict__ C, int M, int N, int K) {
  __shared__ unsigned short a_lds[128 * 32];
  __shared__ unsigned short b_lds[128 * 32];
  int tid = threadIdx.x;
  int w = tid >> 6, l = tid & 63;
  int wr = w >> 1, wc = w & 1;
  int lr = l & 15, lg = l >> 4;
  int m0 = blockIdx.y * 128, n0 = blockIdx.x * 128;

  int r = tid >> 2;
  int scol = ((tid & 3) ^ (r & 3)) * 8;
  const unsigned short* gA = A + (size_t)(m0 + r) * K + scol;
  const unsigned short* gA2 = gA + (size_t)64 * K;
  const unsigned short* gB = Bt + (size_t)(n0 + r) * K + scol;
  const unsigned short* gB2 = gB + (size_t)64 * K;
  unsigned short* la = &a_lds[w * 512];
  unsigned short* la2 = &a_lds[2048 + w * 512];
  unsigned short* lb = &b_lds[w * 512];
  unsigned short* lb2 = &b_lds[2048 + w * 512];

  int xoff = (lg ^ (lr & 3)) * 8;

  f32x4 acc[4][4] = {};

  for (int k0 = 0; k0 < K; k0 += 32) {
    gload_lds16(gA + k0, la);
    gload_lds16(gA2 + k0, la2);
    gload_lds16(gB + k0, lb);
    gload_lds16(gB2 + k0, lb2);
    __syncthreads();
    bf16x8 af[4], bfr[4];
#pragma unroll
    for (int m = 0; m < 4; m++)
      af[m] = *(const bf16x8*)&a_lds[(wr * 64 + m * 16 + lr) * 32 + xoff];
#pragma unroll
    for (int n = 0; n < 4; n++)
      bfr[n] = *(const bf16x8*)&b_lds[(wc * 64 + n * 16 + lr) * 32 + xoff];
#pragma unroll
    for (int m = 0; m < 4; m++)
#pragma unroll
      for (int n = 0; n < 4; n++)
        acc[m][n] = __builtin_amdgcn_mfma_f32_16x16x32_bf16(af[m], bfr[n], acc[m][n], 0, 0, 0);
    __syncthreads();
  }

#pragma unroll
  for (int m = 0; m < 4; m++)
#pragma unroll
    for (int n = 0; n < 4; n++)
#pragma unroll
      for (int i = 0; i < 4; i++) {
        size_t row = (size_t)(m0 + wr * 64 + m * 16 + lg * 4 + i);
        size_t col = (size_t)(n0 + wc * 64 + n * 16 + lr);
        store_val(&C[row * N + col], acc[m][n][i]);
      }
}

// ---------------- flash attention, causal ----------------
// 4 independent waves/block (no barriers). Swapped QK^T: lane holds S^T[k][q=lr].
// In-lane row reduce + 2 shuffles; exp2-domain softmax; defer-max; cvt_pk P->bf16;
// per-wave XOR-swizzled P strip in LDS.
__global__ __launch_bounds__(256, 4) void attn_kernel(const unsigned short* __restrict__ qkv,
                                                      const unsigned short* __restrict__ vt,
                                                      unsigned short* __restrict__ y) {
  __shared__ unsigned short p_lds[4][16 * 64];
  int tid = threadIdx.x;
  int w = tid >> 6, l = tid & 63;
  int lr = l & 15, lg = l >> 4;
  int g4 = lg * 4;
  int lhi = l & 48;
  int bh = blockIdx.x;
  int b = bh >> 4, h = bh & 15;
  int q0 = blockIdx.y * 64 + w * 16;

  char* pl = (char*)p_lds[w];

  const unsigned short* qp = qkv + (size_t)(b * 2048 + q0 + lr) * 3072 + h * 64 + lg * 8;
  bf16x8 aQ0 = *(const bf16x8*)qp;
  bf16x8 aQ1 = *(const bf16x8*)(qp + 32);

  const unsigned short* kbgl = qkv + (size_t)(b * 2048) * 3072 + 1024 + h * 64 + lg * 8;
  const unsigned short* vbgl = vt + (size_t)bh * 131072 + (size_t)lr * 2048 + lg * 8;

  f32x4 O[4] = {};
  float mrow = -3.0e38f, lsum = 0.f;
  const float SC = 0.125f * 1.44269504f;  // scale * log2(e)

  int nb = (q0 >> 6) + 1;
  for (int kb = 0; kb < nb; kb++) {
    int kbase = kb * 64;
    // --- QK^T (swapped): lane holds S^T[k = kbase+n*16+g4+i][q = q0+lr] ---
    f32x4 sv[4];
#pragma unroll
    for (int n = 0; n < 4; n++) {
      const unsigned short* kp = kbgl + (size_t)(kbase + n * 16 + lr) * 3072;
      bf16x8 kf0 = *(const bf16x8*)kp;
      bf16x8 kf1 = *(const bf16x8*)(kp + 32);
      f32x4 z = {};
      z = __builtin_amdgcn_mfma_f32_16x16x32_bf16(kf0, aQ0, z, 0, 0, 0);
      z = __builtin_amdgcn_mfma_f32_16x16x32_bf16(kf1, aQ1, z, 0, 0, 0);
      sv[n] = z;
    }
    float s2[4][4];
#pragma unroll
    for (int n = 0; n < 4; n++)
#pragma unroll
      for (int i = 0; i < 4; i++) s2[n][i] = sv[n][i] * SC;
    if (kb == nb - 1) {  // wave-uniform: mask only the diagonal tile
#pragma unroll
      for (int n = 0; n < 4; n++)
#pragma unroll
        for (int i = 0; i < 4; i++)
          if (kbase + n * 16 + g4 + i > q0 + lr) s2[n][i] = -1.0e38f;
    }
    // --- row max: 15 in-lane + 2 shuffles ---
    float tm = fmaxf(fmaxf(fmaxf(s2[0][0], s2[0][1]), fmaxf(s2[0][2], s2[0][3])),
                     fmaxf(fmaxf(fmaxf(s2[1][0], s2[1][1]), fmaxf(s2[1][2], s2[1][3])),
                           fmaxf(fmaxf(fmaxf(s2[2][0], s2[2][1]), fmaxf(s2[2][2], s2[2][3])),
                                 fmaxf(fmaxf(s2[3][0], s2[3][1]), fmaxf(s2[3][2], s2[3][3])))));
    tm = fmaxf(tm, __shfl_xor(tm, 16));
    tm = fmaxf(tm, __shfl_xor(tm, 32));
    // --- defer-max rescale (threshold 8 nats = 11.54 bits) ---
    if (__any(tm > mrow + 11.54f)) {
      float mnew = fmaxf(mrow, tm);
      float fac = __builtin_amdgcn_exp2f(mrow - mnew);
      mrow = mnew;
      lsum *= fac;
      float f0 = __shfl(fac, lhi | g4);
      float f1 = __shfl(fac, lhi | (g4 + 1));
      float f2 = __shfl(fac, lhi | (g4 + 2));
      float f3 = __shfl(fac, lhi | (g4 + 3));
#pragma unroll
      for (int n2 = 0; n2 < 4; n2++) {
        O[n2][0] *= f0; O[n2][1] *= f1; O[n2][2] *= f2; O[n2][3] *= f3;
      }
    }
    // --- P = exp2(s2 - m), row sum, pack to bf16 ---
    float psum = 0.f;
    unsigned pk0[4], pk1[4];
#pragma unroll
    for (int n = 0; n < 4; n++) {
      float p0 = __builtin_amdgcn_exp2f(s2[n][0] - mrow);
      float p1 = __builtin_amdgcn_exp2f(s2[n][1] - mrow);
      float p2 = __builtin_amdgcn_exp2f(s2[n][2] - mrow);
      float p3 = __builtin_amdgcn_exp2f(s2[n][3] - mrow);
      psum += (p0 + p1) + (p2 + p3);
      pk0[n] = cvt_pk_bf16(p0, p1);
      pk1[n] = cvt_pk_bf16(p2, p3);
    }
    psum += __shfl_xor(psum, 16);
    psum += __shfl_xor(psum, 32);
    lsum += psum;
    // --- P^T regs -> LDS as P[q=lr][k], XOR-swizzled 16B chunks ---
#pragma unroll
    for (int n = 0; n < 4; n++) {
      int chunk = (2 * n + (lg >> 1)) ^ (lr & 7);
      *(uint2*)(pl + lr * 128 + chunk * 16 + (lg & 1) * 8) = make_uint2(pk0[n], pk1[n]);
    }
    // --- PV: A-frag = P rows from LDS, B-frag = V^T rows from global ---
    bf16x8 aP0 = *(const bf16x8*)(pl + lr * 128 + (lg ^ (lr & 7)) * 16);
    bf16x8 aP1 = *(const bf16x8*)(pl + lr * 128 + ((4 + lg) ^ (lr & 7)) * 16);
#pragma unroll
    for (int n2 = 0; n2 < 4; n2++) {
      const unsigned short* vp = vbgl + (size_t)(n2 * 16) * 2048 + kbase;
      bf16x8 v0 = *(const bf16x8*)vp;
      bf16x8 v1 = *(const bf16x8*)(vp + 32);
      O[n2] = __builtin_amdgcn_mfma_f32_16x16x32_bf16(aP0, v0, O[n2], 0, 0, 0);
      O[n2] = __builtin_amdgcn_mfma_f32_16x16x32_bf16(aP1, v1, O[n2], 0, 0, 0);
    }
  }
  // --- epilogue: broadcast lsum to O-layout, divide, store ---
  float s0 = __shfl(lsum, lhi | g4);
  float s1 = __shfl(lsum, lhi | (g4 + 1));
  float s2v = __shfl(lsum, lhi | (g4 + 2));
  float s3 = __shfl(lsum, lhi | (g4 + 3));
  float r0 = 1.f / s0, r1 = 1.f / s1, r2 = 1.f / s2v, r3 = 1.f / s3;
#pragma unroll
  for (int n2 = 0; n2 < 4; n2++) {
    y[(size_t)(b * 2048 + q0 + g4 + 0) * 1024 + h * 64 + n2 * 16 + lr] = f2bf(O[n2][0] * r0);
    y[(size_t)(b * 2048 + q0 + g4 + 1) * 1024 + h * 64 + n2 * 16 + lr] = f2bf(O[n2][1] * r1);
    y[(size_t)(b * 2048 + q0 + g4 + 2) * 1024 + h * 64 + n2 * 16 + lr] = f2bf(O[n2][2] * r2);
    y[(size_t)(b * 2048 + q0 + g4 + 3) * 1024 + h * 64 + n2 * 16 + lr] = f2bf(O[n2][3] * r3);
  }
}

extern "C" void kernel_launch(void* const* d_in, const int* in_sizes, int n_in,
                              void* d_out, int out_size, void* d_ws, size_t ws_size,
                              hipStream_t stream) {
  const float* x = (const float*)d_in[0];
  const float* Wa = (const float*)d_in[1];
  const float* Wp = (const float*)d_in[2];
  float* out = (float*)d_out;

  char* ws = (char*)d_ws;
  size_t off = 0;
  unsigned short* xb = (unsigned short*)(ws + off);   off += (size_t)8192 * 1024 * 2;
  unsigned short* Wta = (unsigned short*)(ws + off);  off += (size_t)3072 * 1024 * 2;
  unsigned short* Wtp = (unsigned short*)(ws + off);  off += (size_t)1024 * 1024 * 2;
  unsigned short* qkvb = (unsigned short*)(ws + off); off += (size_t)8192 * 3072 * 2;
  unsigned short* vtb = (unsigned short*)(ws + off);  off += (size_t)64 * 64 * 2048 * 2;
  unsigned short* yb = (unsigned short*)(ws + off);   off += (size_t)8192 * 1024 * 2;

  f2bf_kernel<<<2048, 256, 0, stream>>>(x, xb, 8192 * 1024);
  transpose_f2bf<<<dim3(48, 16), 256, 0, stream>>>(Wa, Wta, 1024, 3072);
  transpose_f2bf<<<dim3(16, 16), 256, 0, stream>>>(Wp, Wtp, 1024, 1024);
  gemm_bt<unsigned short><<<dim3(24, 64), 256, 0, stream>>>(xb, Wta, qkvb, 8192, 3072, 1024);
  make_vt<<<dim3(64, 32), 256, 0, stream>>>(qkvb, vtb);
  attn_kernel<<<dim3(64, 32), 256, 0, stream>>>(qkvb, vtb, yb);
  gemm_bt<float><<<dim3(8, 64), 256, 0, stream>>>(yb, Wtp, out, 8192, 1024, 1024);
}

// Round 3
// 260.087 us; speedup vs baseline: 1.4841x; 1.4665x over previous
//
#include <hip/hip_runtime.h>
#include <stdint.h>

typedef __bf16 bf16x8 __attribute__((ext_vector_type(8)));
typedef float f32x4 __attribute__((ext_vector_type(4)));

__device__ __forceinline__ unsigned short f2bf(float f) {
  unsigned u = __builtin_bit_cast(unsigned, f);
  u = (u + 0x7fffu + ((u >> 16) & 1u)) >> 16;
  return (unsigned short)u;
}

__device__ __forceinline__ unsigned cvt_pk_bf16(float a, float b) {
  unsigned r;
  asm("v_cvt_pk_bf16_f32 %0, %1, %2" : "=v"(r) : "v"(a), "v"(b));
  return r;
}

__device__ __forceinline__ void gload_lds16(const unsigned short* g, unsigned short* l) {
  __builtin_amdgcn_global_load_lds(
      (__attribute__((address_space(1))) unsigned int*)g,
      (__attribute__((address_space(3))) unsigned int*)l, 16, 0, 0);
}

__device__ __forceinline__ void store_val(float* p, float v) { *p = v; }
__device__ __forceinline__ void store_val(unsigned short* p, float v) { *p = f2bf(v); }

// ---------------- fp32 -> bf16 convert ----------------
__global__ __launch_bounds__(256) void f2bf_kernel(const float* __restrict__ in,
                                                   unsigned short* __restrict__ out, int n) {
  int stride = gridDim.x * blockDim.x * 4;
  for (int i = (blockIdx.x * blockDim.x + threadIdx.x) * 4; i < n; i += stride) {
    float4 v = *(const float4*)(in + i);
    ushort4 o;
    o.x = f2bf(v.x); o.y = f2bf(v.y); o.z = f2bf(v.z); o.w = f2bf(v.w);
    *(ushort4*)(out + i) = o;
  }
}

// ---------------- transpose fp32 [R][C] -> bf16 [C][R] ----------------
__global__ __launch_bounds__(256) void transpose_f2bf(const float* __restrict__ in,
                                                      unsigned short* __restrict__ out,
                                                      int R, int Ccols) {
  __shared__ unsigned short t[64][65];
  int r0 = blockIdx.y * 64, c0 = blockIdx.x * 64;
  int tid = threadIdx.x;
#pragma unroll
  for (int rep = 0; rep < 16; rep++) {
    int idx = rep * 256 + tid;
    int rr = idx >> 6, cc = idx & 63;
    t[rr][cc] = f2bf(in[(size_t)(r0 + rr) * Ccols + c0 + cc]);
  }
  __syncthreads();
#pragma unroll
  for (int rep = 0; rep < 16; rep++) {
    int idx = rep * 256 + tid;
    int cc = idx >> 6, rr = idx & 63;
    out[(size_t)(c0 + cc) * R + r0 + rr] = t[rr][cc];
  }
}

// ---------------- build V^T per head: vt[bh][d][t] from qkv ----------------
__global__ __launch_bounds__(256) void make_vt(const unsigned short* __restrict__ qkv,
                                               unsigned short* __restrict__ vt) {
  __shared__ unsigned short t[64][65];
  int bh = blockIdx.x;
  int b = bh >> 4, h = bh & 15;
  int t0 = blockIdx.y * 64;
  int tid = threadIdx.x;
#pragma unroll
  for (int rep = 0; rep < 16; rep++) {
    int idx = rep * 256 + tid;
    int tt = idx >> 6, dd = idx & 63;
    t[tt][dd] = qkv[(size_t)(b * 2048 + t0 + tt) * 3072 + 2048 + h * 64 + dd];
  }
  __syncthreads();
#pragma unroll
  for (int rep = 0; rep < 16; rep++) {
    int idx = rep * 256 + tid;
    int dd = idx >> 6, tt = idx & 63;
    vt[(size_t)bh * 131072 + (size_t)dd * 2048 + t0 + tt] = t[tt][dd];
  }
}

// ---------------- bf16 GEMM: C[M][N] = A[M][K] * Bt[N][K]^T ----------------
template <typename OutT>
__global__ __launch_bounds__(256) void gemm_bt(const unsigned short* __restrict__ A,
                                               const unsigned short* __restrict__ Bt,
                                               OutT* __restrict__ C, int M, int N, int K) {
  __shared__ unsigned short a_lds[128 * 32];
  __shared__ unsigned short b_lds[128 * 32];
  int tid = threadIdx.x;
  int w = tid >> 6, l = tid & 63;
  int wr = w >> 1, wc = w & 1;
  int lr = l & 15, lg = l >> 4;
  int m0 = blockIdx.y * 128, n0 = blockIdx.x * 128;

  int r = tid >> 2;
  int scol = ((tid & 3) ^ (r & 3)) * 8;
  const unsigned short* gA = A + (size_t)(m0 + r) * K + scol;
  const unsigned short* gA2 = gA + (size_t)64 * K;
  const unsigned short* gB = Bt + (size_t)(n0 + r) * K + scol;
  const unsigned short* gB2 = gB + (size_t)64 * K;
  unsigned short* la = &a_lds[w * 512];
  unsigned short* la2 = &a_lds[2048 + w * 512];
  unsigned short* lb = &b_lds[w * 512];
  unsigned short* lb2 = &b_lds[2048 + w * 512];

  int xoff = (lg ^ (lr & 3)) * 8;

  f32x4 acc[4][4] = {};

  for (int k0 = 0; k0 < K; k0 += 32) {
    gload_lds16(gA + k0, la);
    gload_lds16(gA2 + k0, la2);
    gload_lds16(gB + k0, lb);
    gload_lds16(gB2 + k0, lb2);
    __syncthreads();
    bf16x8 af[4], bfr[4];
#pragma unroll
    for (int m = 0; m < 4; m++)
      af[m] = *(const bf16x8*)&a_lds[(wr * 64 + m * 16 + lr) * 32 + xoff];
#pragma unroll
    for (int n = 0; n < 4; n++)
      bfr[n] = *(const bf16x8*)&b_lds[(wc * 64 + n * 16 + lr) * 32 + xoff];
#pragma unroll
    for (int m = 0; m < 4; m++)
#pragma unroll
      for (int n = 0; n < 4; n++)
        acc[m][n] = __builtin_amdgcn_mfma_f32_16x16x32_bf16(af[m], bfr[n], acc[m][n], 0, 0, 0);
    __syncthreads();
  }

#pragma unroll
  for (int m = 0; m < 4; m++)
#pragma unroll
    for (int n = 0; n < 4; n++)
#pragma unroll
      for (int i = 0; i < 4; i++) {
        size_t row = (size_t)(m0 + wr * 64 + m * 16 + lg * 4 + i);
        size_t col = (size_t)(n0 + wc * 64 + n * 16 + lr);
        store_val(&C[row * N + col], acc[m][n][i]);
      }
}

// ---------------- flash attention, causal ----------------
// 4 independent waves/block, each wave owns 32 q-rows (two 16-col S^T fragments
// sharing K/V loads). Swapped QK^T, exp2 softmax, defer-max, cvt_pk packing,
// per-wave swizzled P strips. Heavy-first dispatch order for causal balance.
__global__ __launch_bounds__(256, 2) void attn_kernel(const unsigned short* __restrict__ qkv,
                                                      const unsigned short* __restrict__ vt,
                                                      unsigned short* __restrict__ y) {
  __shared__ unsigned short p_lds[8][16 * 64];
  int tid = threadIdx.x;
  int w = tid >> 6, l = tid & 63;
  int lr = l & 15, lg = l >> 4;
  int g4 = lg * 4;
  int lband = l & 48;
  int bh = blockIdx.x;
  int b = bh >> 4, h = bh & 15;
  int qgrp = 15 - blockIdx.y;           // heavy-first
  int q0 = qgrp * 128 + w * 32;

  char* plo = (char*)p_lds[w * 2];
  char* phi = (char*)p_lds[w * 2 + 1];

  const unsigned short* qp = qkv + (size_t)(b * 2048 + q0 + lr) * 3072 + h * 64 + lg * 8;
  bf16x8 aQ0lo = *(const bf16x8*)qp;
  bf16x8 aQ1lo = *(const bf16x8*)(qp + 32);
  bf16x8 aQ0hi = *(const bf16x8*)(qp + 16 * 3072);
  bf16x8 aQ1hi = *(const bf16x8*)(qp + 16 * 3072 + 32);

  const unsigned short* kbgl = qkv + (size_t)(b * 2048) * 3072 + 1024 + h * 64 + lg * 8;
  const unsigned short* vbgl = vt + (size_t)bh * 131072 + (size_t)lr * 2048 + lg * 8;

  f32x4 Olo[4] = {}, Ohi[4] = {};
  float mlo = -3.0e38f, mhi = -3.0e38f;
  float sumlo = 0.f, sumhi = 0.f;
  const float SC = 0.125f * 1.44269504f;

  int nb = (q0 >> 6) + 1;
  for (int kb = 0; kb < nb; kb++) {
    int kbase = kb * 64;
    // --- issue ALL K and V fragment loads up front (16 independent loads) ---
    bf16x8 kf[4][2], vf[4][2];
#pragma unroll
    for (int n = 0; n < 4; n++) {
      const unsigned short* kp = kbgl + (size_t)(kbase + n * 16 + lr) * 3072;
      kf[n][0] = *(const bf16x8*)kp;
      kf[n][1] = *(const bf16x8*)(kp + 32);
    }
#pragma unroll
    for (int n2 = 0; n2 < 4; n2++) {
      const unsigned short* vp = vbgl + (size_t)(n2 * 16) * 2048 + kbase;
      vf[n2][0] = *(const bf16x8*)vp;
      vf[n2][1] = *(const bf16x8*)(vp + 32);
    }
    // --- QK^T swapped: lane holds S^T[k][q] for both q-halves ---
    f32x4 svlo[4], svhi[4];
    __builtin_amdgcn_s_setprio(1);
#pragma unroll
    for (int n = 0; n < 4; n++) {
      f32x4 z = {};
      z = __builtin_amdgcn_mfma_f32_16x16x32_bf16(kf[n][0], aQ0lo, z, 0, 0, 0);
      z = __builtin_amdgcn_mfma_f32_16x16x32_bf16(kf[n][1], aQ1lo, z, 0, 0, 0);
      svlo[n] = z;
      f32x4 z2 = {};
      z2 = __builtin_amdgcn_mfma_f32_16x16x32_bf16(kf[n][0], aQ0hi, z2, 0, 0, 0);
      z2 = __builtin_amdgcn_mfma_f32_16x16x32_bf16(kf[n][1], aQ1hi, z2, 0, 0, 0);
      svhi[n] = z2;
    }
    __builtin_amdgcn_s_setprio(0);
    float slo[4][4], shi[4][4];
#pragma unroll
    for (int n = 0; n < 4; n++)
#pragma unroll
      for (int i = 0; i < 4; i++) {
        slo[n][i] = svlo[n][i] * SC;
        shi[n][i] = svhi[n][i] * SC;
      }
    if (kb == nb - 1) {  // wave-uniform: mask only the diagonal tile
#pragma unroll
      for (int n = 0; n < 4; n++)
#pragma unroll
        for (int i = 0; i < 4; i++) {
          int kk = kbase + n * 16 + g4 + i;
          if (kk > q0 + lr) slo[n][i] = -1.0e38f;
          if (kk > q0 + 16 + lr) shi[n][i] = -1.0e38f;
        }
    }
    // --- row max per half: 15 in-lane + 2 shuffles ---
    float tmlo = fmaxf(
        fmaxf(fmaxf(fmaxf(slo[0][0], slo[0][1]), fmaxf(slo[0][2], slo[0][3])),
              fmaxf(fmaxf(slo[1][0], slo[1][1]), fmaxf(slo[1][2], slo[1][3]))),
        fmaxf(fmaxf(fmaxf(slo[2][0], slo[2][1]), fmaxf(slo[2][2], slo[2][3])),
              fmaxf(fmaxf(slo[3][0], slo[3][1]), fmaxf(slo[3][2], slo[3][3]))));
    float tmhi = fmaxf(
        fmaxf(fmaxf(fmaxf(shi[0][0], shi[0][1]), fmaxf(shi[0][2], shi[0][3])),
              fmaxf(fmaxf(shi[1][0], shi[1][1]), fmaxf(shi[1][2], shi[1][3]))),
        fmaxf(fmaxf(fmaxf(shi[2][0], shi[2][1]), fmaxf(shi[2][2], shi[2][3])),
              fmaxf(fmaxf(shi[3][0], shi[3][1]), fmaxf(shi[3][2], shi[3][3]))));
    tmlo = fmaxf(tmlo, __shfl_xor(tmlo, 16));
    tmlo = fmaxf(tmlo, __shfl_xor(tmlo, 32));
    tmhi = fmaxf(tmhi, __shfl_xor(tmhi, 16));
    tmhi = fmaxf(tmhi, __shfl_xor(tmhi, 32));
    // --- defer-max rescale ---
    if (__any(tmlo > mlo + 11.54f || tmhi > mhi + 11.54f)) {
      float mnlo = fmaxf(mlo, tmlo), mnhi = fmaxf(mhi, tmhi);
      float faclo = __builtin_amdgcn_exp2f(mlo - mnlo);
      float fachi = __builtin_amdgcn_exp2f(mhi - mnhi);
      mlo = mnlo; mhi = mnhi;
      sumlo *= faclo; sumhi *= fachi;
      float f0 = __shfl(faclo, lband | g4);
      float f1 = __shfl(faclo, lband | (g4 + 1));
      float f2 = __shfl(faclo, lband | (g4 + 2));
      float f3 = __shfl(faclo, lband | (g4 + 3));
      float h0 = __shfl(fachi, lband | g4);
      float h1 = __shfl(fachi, lband | (g4 + 1));
      float h2 = __shfl(fachi, lband | (g4 + 2));
      float h3 = __shfl(fachi, lband | (g4 + 3));
#pragma unroll
      for (int n2 = 0; n2 < 4; n2++) {
        Olo[n2][0] *= f0; Olo[n2][1] *= f1; Olo[n2][2] *= f2; Olo[n2][3] *= f3;
        Ohi[n2][0] *= h0; Ohi[n2][1] *= h1; Ohi[n2][2] *= h2; Ohi[n2][3] *= h3;
      }
    }
    // --- P = exp2(s - m), row sums, pack to bf16 ---
    float pslo = 0.f, pshi = 0.f;
    unsigned pk0lo[4], pk1lo[4], pk0hi[4], pk1hi[4];
#pragma unroll
    for (int n = 0; n < 4; n++) {
      float a0 = __builtin_amdgcn_exp2f(slo[n][0] - mlo);
      float a1 = __builtin_amdgcn_exp2f(slo[n][1] - mlo);
      float a2 = __builtin_amdgcn_exp2f(slo[n][2] - mlo);
      float a3 = __builtin_amdgcn_exp2f(slo[n][3] - mlo);
      pslo += (a0 + a1) + (a2 + a3);
      pk0lo[n] = cvt_pk_bf16(a0, a1);
      pk1lo[n] = cvt_pk_bf16(a2, a3);
      float c0 = __builtin_amdgcn_exp2f(shi[n][0] - mhi);
      float c1 = __builtin_amdgcn_exp2f(shi[n][1] - mhi);
      float c2 = __builtin_amdgcn_exp2f(shi[n][2] - mhi);
      float c3 = __builtin_amdgcn_exp2f(shi[n][3] - mhi);
      pshi += (c0 + c1) + (c2 + c3);
      pk0hi[n] = cvt_pk_bf16(c0, c1);
      pk1hi[n] = cvt_pk_bf16(c2, c3);
    }
    pslo += __shfl_xor(pslo, 16);
    pslo += __shfl_xor(pslo, 32);
    pshi += __shfl_xor(pshi, 16);
    pshi += __shfl_xor(pshi, 32);
    sumlo += pslo;
    sumhi += pshi;
    // --- P^T regs -> LDS as P[q=lr][k], XOR-swizzled 16B chunks ---
#pragma unroll
    for (int n = 0; n < 4; n++) {
      int chunk = (2 * n + (lg >> 1)) ^ (lr & 7);
      int off = lr * 128 + chunk * 16 + (lg & 1) * 8;
      *(uint2*)(plo + off) = make_uint2(pk0lo[n], pk1lo[n]);
      *(uint2*)(phi + off) = make_uint2(pk0hi[n], pk1hi[n]);
    }
    bf16x8 aPlo0 = *(const bf16x8*)(plo + lr * 128 + (lg ^ (lr & 7)) * 16);
    bf16x8 aPlo1 = *(const bf16x8*)(plo + lr * 128 + ((4 + lg) ^ (lr & 7)) * 16);
    bf16x8 aPhi0 = *(const bf16x8*)(phi + lr * 128 + (lg ^ (lr & 7)) * 16);
    bf16x8 aPhi1 = *(const bf16x8*)(phi + lr * 128 + ((4 + lg) ^ (lr & 7)) * 16);
    // --- PV: shared V frags serve both halves ---
    __builtin_amdgcn_s_setprio(1);
#pragma unroll
    for (int n2 = 0; n2 < 4; n2++) {
      Olo[n2] = __builtin_amdgcn_mfma_f32_16x16x32_bf16(aPlo0, vf[n2][0], Olo[n2], 0, 0, 0);
      Olo[n2] = __builtin_amdgcn_mfma_f32_16x16x32_bf16(aPlo1, vf[n2][1], Olo[n2], 0, 0, 0);
      Ohi[n2] = __builtin_amdgcn_mfma_f32_16x16x32_bf16(aPhi0, vf[n2][0], Ohi[n2], 0, 0, 0);
      Ohi[n2] = __builtin_amdgcn_mfma_f32_16x16x32_bf16(aPhi1, vf[n2][1], Ohi[n2], 0, 0, 0);
    }
    __builtin_amdgcn_s_setprio(0);
  }
  // --- epilogue ---
  float s0 = __shfl(sumlo, lband | g4);
  float s1 = __shfl(sumlo, lband | (g4 + 1));
  float s2 = __shfl(sumlo, lband | (g4 + 2));
  float s3 = __shfl(sumlo, lband | (g4 + 3));
  float t0 = __shfl(sumhi, lband | g4);
  float t1 = __shfl(sumhi, lband | (g4 + 1));
  float t2 = __shfl(sumhi, lband | (g4 + 2));
  float t3 = __shfl(sumhi, lband | (g4 + 3));
  float rl0 = 1.f / s0, rl1 = 1.f / s1, rl2 = 1.f / s2, rl3 = 1.f / s3;
  float rh0 = 1.f / t0, rh1 = 1.f / t1, rh2 = 1.f / t2, rh3 = 1.f / t3;
#pragma unroll
  for (int n2 = 0; n2 < 4; n2++) {
    size_t base = (size_t)(b * 2048 + q0 + g4) * 1024 + h * 64 + n2 * 16 + lr;
    y[base] = f2bf(Olo[n2][0] * rl0);
    y[base + 1024] = f2bf(Olo[n2][1] * rl1);
    y[base + 2048] = f2bf(Olo[n2][2] * rl2);
    y[base + 3072] = f2bf(Olo[n2][3] * rl3);
    size_t bhh = base + (size_t)16 * 1024;
    y[bhh] = f2bf(Ohi[n2][0] * rh0);
    y[bhh + 1024] = f2bf(Ohi[n2][1] * rh1);
    y[bhh + 2048] = f2bf(Ohi[n2][2] * rh2);
    y[bhh + 3072] = f2bf(Ohi[n2][3] * rh3);
  }
}

extern "C" void kernel_launch(void* const* d_in, const int* in_sizes, int n_in,
                              void* d_out, int out_size, void* d_ws, size_t ws_size,
                              hipStream_t stream) {
  const float* x = (const float*)d_in[0];
  const float* Wa = (const float*)d_in[1];
  const float* Wp = (const float*)d_in[2];
  float* out = (float*)d_out;

  char* ws = (char*)d_ws;
  size_t off = 0;
  unsigned short* xb = (unsigned short*)(ws + off);   off += (size_t)8192 * 1024 * 2;
  unsigned short* Wta = (unsigned short*)(ws + off);  off += (size_t)3072 * 1024 * 2;
  unsigned short* Wtp = (unsigned short*)(ws + off);  off += (size_t)1024 * 1024 * 2;
  unsigned short* qkvb = (unsigned short*)(ws + off); off += (size_t)8192 * 3072 * 2;
  unsigned short* vtb = (unsigned short*)(ws + off);  off += (size_t)64 * 64 * 2048 * 2;
  unsigned short* yb = (unsigned short*)(ws + off);   off += (size_t)8192 * 1024 * 2;

  f2bf_kernel<<<2048, 256, 0, stream>>>(x, xb, 8192 * 1024);
  transpose_f2bf<<<dim3(48, 16), 256, 0, stream>>>(Wa, Wta, 1024, 3072);
  transpose_f2bf<<<dim3(16, 16), 256, 0, stream>>>(Wp, Wtp, 1024, 1024);
  gemm_bt<unsigned short><<<dim3(24, 64), 256, 0, stream>>>(xb, Wta, qkvb, 8192, 3072, 1024);
  make_vt<<<dim3(64, 32), 256, 0, stream>>>(qkvb, vtb);
  attn_kernel<<<dim3(64, 16), 256, 0, stream>>>(qkvb, vtb, yb);
  gemm_bt<float><<<dim3(8, 64), 256, 0, stream>>>(yb, Wtp, out, 8192, 1024, 1024);
}

// Round 4
// 191.275 us; speedup vs baseline: 2.0181x; 1.3598x over previous
//
#include <hip/hip_runtime.h>
#include <stdint.h>

typedef __bf16 bf16x8 __attribute__((ext_vector_type(8)));
typedef float f32x4 __attribute__((ext_vector_type(4)));

__device__ __forceinline__ unsigned short f2bf(float f) {
  unsigned u = __builtin_bit_cast(unsigned, f);
  u = (u + 0x7fffu + ((u >> 16) & 1u)) >> 16;
  return (unsigned short)u;
}

__device__ __forceinline__ unsigned cvt_pk_bf16(float a, float b) {
  unsigned r;
  asm("v_cvt_pk_bf16_f32 %0, %1, %2" : "=v"(r) : "v"(a), "v"(b));
  return r;
}

__device__ __forceinline__ void gload_lds16(const unsigned short* g, unsigned short* l) {
  __builtin_amdgcn_global_load_lds(
      (__attribute__((address_space(1))) unsigned int*)g,
      (__attribute__((address_space(3))) unsigned int*)l, 16, 0, 0);
}

__device__ __forceinline__ void store_val(float* p, float v) { *p = v; }
__device__ __forceinline__ void store_val(unsigned short* p, float v) { *p = f2bf(v); }

// ---------------- fp32 -> bf16 convert ----------------
__global__ __launch_bounds__(256) void f2bf_kernel(const float* __restrict__ in,
                                                   unsigned short* __restrict__ out, int n) {
  int stride = gridDim.x * blockDim.x * 4;
  for (int i = (blockIdx.x * blockDim.x + threadIdx.x) * 4; i < n; i += stride) {
    float4 v = *(const float4*)(in + i);
    ushort4 o;
    o.x = f2bf(v.x); o.y = f2bf(v.y); o.z = f2bf(v.z); o.w = f2bf(v.w);
    *(ushort4*)(out + i) = o;
  }
}

// ---------------- transpose fp32 [R][C] -> bf16 [C][R] ----------------
__global__ __launch_bounds__(256) void transpose_f2bf(const float* __restrict__ in,
                                                      unsigned short* __restrict__ out,
                                                      int R, int Ccols) {
  __shared__ unsigned short t[64][65];
  int r0 = blockIdx.y * 64, c0 = blockIdx.x * 64;
  int tid = threadIdx.x;
#pragma unroll
  for (int rep = 0; rep < 16; rep++) {
    int idx = rep * 256 + tid;
    int rr = idx >> 6, cc = idx & 63;
    t[rr][cc] = f2bf(in[(size_t)(r0 + rr) * Ccols + c0 + cc]);
  }
  __syncthreads();
#pragma unroll
  for (int rep = 0; rep < 16; rep++) {
    int idx = rep * 256 + tid;
    int cc = idx >> 6, rr = idx & 63;
    out[(size_t)(c0 + cc) * R + r0 + rr] = t[rr][cc];
  }
}

// ---------------- build V^T per head: vt[bh][d][t] from qkv ----------------
__global__ __launch_bounds__(256) void make_vt(const unsigned short* __restrict__ qkv,
                                               unsigned short* __restrict__ vt) {
  __shared__ unsigned short t[64][65];
  int bh = blockIdx.x;
  int b = bh >> 4, h = bh & 15;
  int t0 = blockIdx.y * 64;
  int tid = threadIdx.x;
#pragma unroll
  for (int rep = 0; rep < 16; rep++) {
    int idx = rep * 256 + tid;
    int tt = idx >> 6, dd = idx & 63;
    t[tt][dd] = qkv[(size_t)(b * 2048 + t0 + tt) * 3072 + 2048 + h * 64 + dd];
  }
  __syncthreads();
#pragma unroll
  for (int rep = 0; rep < 16; rep++) {
    int idx = rep * 256 + tid;
    int dd = idx >> 6, tt = idx & 63;
    vt[(size_t)bh * 131072 + (size_t)dd * 2048 + t0 + tt] = t[tt][dd];
  }
}

// ---------------- bf16 GEMM: C[M][N] = A[M][K] * Bt[N][K]^T ----------------
template <typename OutT>
__global__ __launch_bounds__(256) void gemm_bt(const unsigned short* __restrict__ A,
                                               const unsigned short* __restrict__ Bt,
                                               OutT* __restrict__ C, int M, int N, int K) {
  __shared__ unsigned short a_lds[128 * 32];
  __shared__ unsigned short b_lds[128 * 32];
  int tid = threadIdx.x;
  int w = tid >> 6, l = tid & 63;
  int wr = w >> 1, wc = w & 1;
  int lr = l & 15, lg = l >> 4;
  int m0 = blockIdx.y * 128, n0 = blockIdx.x * 128;

  int r = tid >> 2;
  int scol = ((tid & 3) ^ (r & 3)) * 8;
  const unsigned short* gA = A + (size_t)(m0 + r) * K + scol;
  const unsigned short* gA2 = gA + (size_t)64 * K;
  const unsigned short* gB = Bt + (size_t)(n0 + r) * K + scol;
  const unsigned short* gB2 = gB + (size_t)64 * K;
  unsigned short* la = &a_lds[w * 512];
  unsigned short* la2 = &a_lds[2048 + w * 512];
  unsigned short* lb = &b_lds[w * 512];
  unsigned short* lb2 = &b_lds[2048 + w * 512];

  int xoff = (lg ^ (lr & 3)) * 8;

  f32x4 acc[4][4] = {};

  for (int k0 = 0; k0 < K; k0 += 32) {
    gload_lds16(gA + k0, la);
    gload_lds16(gA2 + k0, la2);
    gload_lds16(gB + k0, lb);
    gload_lds16(gB2 + k0, lb2);
    __syncthreads();
    bf16x8 af[4], bfr[4];
#pragma unroll
    for (int m = 0; m < 4; m++)
      af[m] = *(const bf16x8*)&a_lds[(wr * 64 + m * 16 + lr) * 32 + xoff];
#pragma unroll
    for (int n = 0; n < 4; n++)
      bfr[n] = *(const bf16x8*)&b_lds[(wc * 64 + n * 16 + lr) * 32 + xoff];
#pragma unroll
    for (int m = 0; m < 4; m++)
#pragma unroll
      for (int n = 0; n < 4; n++)
        acc[m][n] = __builtin_amdgcn_mfma_f32_16x16x32_bf16(af[m], bfr[n], acc[m][n], 0, 0, 0);
    __syncthreads();
  }

#pragma unroll
  for (int m = 0; m < 4; m++)
#pragma unroll
    for (int n = 0; n < 4; n++)
#pragma unroll
      for (int i = 0; i < 4; i++) {
        size_t row = (size_t)(m0 + wr * 64 + m * 16 + lg * 4 + i);
        size_t col = (size_t)(n0 + wc * 64 + n * 16 + lr);
        store_val(&C[row * N + col], acc[m][n][i]);
      }
}

// ---------------- flash attention, causal ----------------
// Block = 4 waves sharing one 128-row q-group. K-tile (64x64) and V^T-tile
// (64x64) staged cooperatively into LDS (global_load_lds w=16, XOR-swizzled
// source chunks), 2-phase double-buffered. Each wave owns 32 q-rows (two
// 16-col swapped-S^T fragments). exp2 softmax, defer-max, cvt_pk P packing.
__global__ __launch_bounds__(256, 2) void attn_kernel(const unsigned short* __restrict__ qkv,
                                                      const unsigned short* __restrict__ vt,
                                                      unsigned short* __restrict__ y) {
  __shared__ unsigned short k_lds[2][64 * 64];
  __shared__ unsigned short v_lds[2][64 * 64];
  __shared__ unsigned short p_lds[8][16 * 64];
  int tid = threadIdx.x;
  int w = tid >> 6, l = tid & 63;
  int lr = l & 15, lg = l >> 4;
  int g4 = lg * 4;
  int lband = l & 48;
  int bh = blockIdx.x;
  int b = bh >> 4, h = bh & 15;
  int qgrp = 15 - blockIdx.y;  // heavy-first
  int q0 = qgrp * 128 + w * 32;

  char* plo = (char*)p_lds[w * 2];
  char* phi = (char*)p_lds[w * 2 + 1];

  // ---- staging thread map: thread covers LDS 16B-chunk (row=tid>>3, chunk=tid&7);
  // swizzled global source chunk = (tid&7) ^ (row&7)  (same for both 32-row passes)
  int srow = tid >> 3;                       // 0..31
  int schunk = (tid & 7) ^ (srow & 7);
  const unsigned short* gK0 = qkv + (size_t)(b * 2048 + srow) * 3072 + 1024 + h * 64 + schunk * 8;
  const unsigned short* gK1 = gK0 + (size_t)32 * 3072;
  const unsigned short* gV0 = vt + (size_t)bh * 131072 + (size_t)srow * 2048 + schunk * 8;
  const unsigned short* gV1 = gV0 + (size_t)32 * 2048;
  int ldsbase0 = w * 512;                    // halfwords, pass 0
  int ldsbase1 = 2048 + w * 512;             // pass 1

  const unsigned short* qp = qkv + (size_t)(b * 2048 + q0 + lr) * 3072 + h * 64 + lg * 8;
  bf16x8 aQ0lo = *(const bf16x8*)qp;
  bf16x8 aQ1lo = *(const bf16x8*)(qp + 32);
  bf16x8 aQ0hi = *(const bf16x8*)(qp + 16 * 3072);
  bf16x8 aQ1hi = *(const bf16x8*)(qp + 16 * 3072 + 32);

  f32x4 Olo[4] = {}, Ohi[4] = {};
  float mlo = -3.0e38f, mhi = -3.0e38f;
  float sumlo = 0.f, sumhi = 0.f;
  const float SC = 0.125f * 1.44269504f;

  // fragment read offsets (inverse swizzle): phys chunk = logical ^ (row&7)
  int rx = lr & 7;
  int kc0 = (lg ^ rx) * 8;          // logical chunks 0..3  (d/t 0..31)
  int kc1 = ((4 + lg) ^ rx) * 8;    // logical chunks 4..7  (d/t 32..63)

  int nbmax = ((qgrp * 128 + 96) >> 6) + 1;
  int kend = q0 + 31;               // last key this wave needs
  int kdiag = q0 >> 6;              // tile needing the causal mask

  // prologue: stage tile 0 into buf 0
  gload_lds16(gK0, &k_lds[0][ldsbase0]);
  gload_lds16(gK1, &k_lds[0][ldsbase1]);
  gload_lds16(gV0, &v_lds[0][ldsbase0]);
  gload_lds16(gV1, &v_lds[0][ldsbase1]);
  __syncthreads();

  int cur = 0;
  for (int kb = 0; kb < nbmax; kb++) {
    int kbase = kb * 64;
    if (kb + 1 < nbmax) {  // stage next tile into other buffer
      size_t koff = (size_t)(kbase + 64) * 3072;
      size_t voff = (size_t)(kbase + 64);
      int nxt = cur ^ 1;
      gload_lds16(gK0 + koff, &k_lds[nxt][ldsbase0]);
      gload_lds16(gK1 + koff, &k_lds[nxt][ldsbase1]);
      gload_lds16(gV0 + voff, &v_lds[nxt][ldsbase0]);
      gload_lds16(gV1 + voff, &v_lds[nxt][ldsbase1]);
    }
    if (kbase <= kend) {  // wave-uniform: skip fully-masked tiles
      const unsigned short* kl = k_lds[cur];
      const unsigned short* vl = v_lds[cur];
      // --- QK^T swapped: lane holds S^T[k][q] for both q-halves ---
      f32x4 svlo[4], svhi[4];
      __builtin_amdgcn_s_setprio(1);
#pragma unroll
      for (int n = 0; n < 4; n++) {
        bf16x8 kf0 = *(const bf16x8*)&kl[(n * 16 + lr) * 64 + kc0];
        bf16x8 kf1 = *(const bf16x8*)&kl[(n * 16 + lr) * 64 + kc1];
        f32x4 z = {};
        z = __builtin_amdgcn_mfma_f32_16x16x32_bf16(kf0, aQ0lo, z, 0, 0, 0);
        z = __builtin_amdgcn_mfma_f32_16x16x32_bf16(kf1, aQ1lo, z, 0, 0, 0);
        svlo[n] = z;
        f32x4 z2 = {};
        z2 = __builtin_amdgcn_mfma_f32_16x16x32_bf16(kf0, aQ0hi, z2, 0, 0, 0);
        z2 = __builtin_amdgcn_mfma_f32_16x16x32_bf16(kf1, aQ1hi, z2, 0, 0, 0);
        svhi[n] = z2;
      }
      __builtin_amdgcn_s_setprio(0);
      float slo[4][4], shi[4][4];
#pragma unroll
      for (int n = 0; n < 4; n++)
#pragma unroll
        for (int i = 0; i < 4; i++) {
          slo[n][i] = svlo[n][i] * SC;
          shi[n][i] = svhi[n][i] * SC;
        }
      if (kb == kdiag) {  // wave-uniform: mask only the diagonal tile
#pragma unroll
        for (int n = 0; n < 4; n++)
#pragma unroll
          for (int i = 0; i < 4; i++) {
            int kk = kbase + n * 16 + g4 + i;
            if (kk > q0 + lr) slo[n][i] = -1.0e38f;
            if (kk > q0 + 16 + lr) shi[n][i] = -1.0e38f;
          }
      }
      // --- row max per half: 15 in-lane + 2 shuffles ---
      float tmlo = fmaxf(
          fmaxf(fmaxf(fmaxf(slo[0][0], slo[0][1]), fmaxf(slo[0][2], slo[0][3])),
                fmaxf(fmaxf(slo[1][0], slo[1][1]), fmaxf(slo[1][2], slo[1][3]))),
          fmaxf(fmaxf(fmaxf(slo[2][0], slo[2][1]), fmaxf(slo[2][2], slo[2][3])),
                fmaxf(fmaxf(slo[3][0], slo[3][1]), fmaxf(slo[3][2], slo[3][3]))));
      float tmhi = fmaxf(
          fmaxf(fmaxf(fmaxf(shi[0][0], shi[0][1]), fmaxf(shi[0][2], shi[0][3])),
                fmaxf(fmaxf(shi[1][0], shi[1][1]), fmaxf(shi[1][2], shi[1][3]))),
          fmaxf(fmaxf(fmaxf(shi[2][0], shi[2][1]), fmaxf(shi[2][2], shi[2][3])),
                fmaxf(fmaxf(shi[3][0], shi[3][1]), fmaxf(shi[3][2], shi[3][3]))));
      tmlo = fmaxf(tmlo, __shfl_xor(tmlo, 16));
      tmlo = fmaxf(tmlo, __shfl_xor(tmlo, 32));
      tmhi = fmaxf(tmhi, __shfl_xor(tmhi, 16));
      tmhi = fmaxf(tmhi, __shfl_xor(tmhi, 32));
      // --- defer-max rescale ---
      if (__any(tmlo > mlo + 11.54f || tmhi > mhi + 11.54f)) {
        float mnlo = fmaxf(mlo, tmlo), mnhi = fmaxf(mhi, tmhi);
        float faclo = __builtin_amdgcn_exp2f(mlo - mnlo);
        float fachi = __builtin_amdgcn_exp2f(mhi - mnhi);
        mlo = mnlo; mhi = mnhi;
        sumlo *= faclo; sumhi *= fachi;
        float f0 = __shfl(faclo, lband | g4);
        float f1 = __shfl(faclo, lband | (g4 + 1));
        float f2 = __shfl(faclo, lband | (g4 + 2));
        float f3 = __shfl(faclo, lband | (g4 + 3));
        float h0 = __shfl(fachi, lband | g4);
        float h1 = __shfl(fachi, lband | (g4 + 1));
        float h2 = __shfl(fachi, lband | (g4 + 2));
        float h3 = __shfl(fachi, lband | (g4 + 3));
#pragma unroll
        for (int n2 = 0; n2 < 4; n2++) {
          Olo[n2][0] *= f0; Olo[n2][1] *= f1; Olo[n2][2] *= f2; Olo[n2][3] *= f3;
          Ohi[n2][0] *= h0; Ohi[n2][1] *= h1; Ohi[n2][2] *= h2; Ohi[n2][3] *= h3;
        }
      }
      // --- P = exp2(s - m), row sums, pack to bf16 ---
      float pslo = 0.f, pshi = 0.f;
      unsigned pk0lo[4], pk1lo[4], pk0hi[4], pk1hi[4];
#pragma unroll
      for (int n = 0; n < 4; n++) {
        float a0 = __builtin_amdgcn_exp2f(slo[n][0] - mlo);
        float a1 = __builtin_amdgcn_exp2f(slo[n][1] - mlo);
        float a2 = __builtin_amdgcn_exp2f(slo[n][2] - mlo);
        float a3 = __builtin_amdgcn_exp2f(slo[n][3] - mlo);
        pslo += (a0 + a1) + (a2 + a3);
        pk0lo[n] = cvt_pk_bf16(a0, a1);
        pk1lo[n] = cvt_pk_bf16(a2, a3);
        float c0 = __builtin_amdgcn_exp2f(shi[n][0] - mhi);
        float c1 = __builtin_amdgcn_exp2f(shi[n][1] - mhi);
        float c2 = __builtin_amdgcn_exp2f(shi[n][2] - mhi);
        float c3 = __builtin_amdgcn_exp2f(shi[n][3] - mhi);
        pshi += (c0 + c1) + (c2 + c3);
        pk0hi[n] = cvt_pk_bf16(c0, c1);
        pk1hi[n] = cvt_pk_bf16(c2, c3);
      }
      pslo += __shfl_xor(pslo, 16);
      pslo += __shfl_xor(pslo, 32);
      pshi += __shfl_xor(pshi, 16);
      pshi += __shfl_xor(pshi, 32);
      sumlo += pslo;
      sumhi += pshi;
      // --- P^T regs -> LDS as P[q=lr][k], XOR-swizzled 16B chunks ---
#pragma unroll
      for (int n = 0; n < 4; n++) {
        int chunk = (2 * n + (lg >> 1)) ^ (lr & 7);
        int off = lr * 128 + chunk * 16 + (lg & 1) * 8;
        *(uint2*)(plo + off) = make_uint2(pk0lo[n], pk1lo[n]);
        *(uint2*)(phi + off) = make_uint2(pk0hi[n], pk1hi[n]);
      }
      bf16x8 aPlo0 = *(const bf16x8*)(plo + lr * 128 + (lg ^ rx) * 16);
      bf16x8 aPlo1 = *(const bf16x8*)(plo + lr * 128 + ((4 + lg) ^ rx) * 16);
      bf16x8 aPhi0 = *(const bf16x8*)(phi + lr * 128 + (lg ^ rx) * 16);
      bf16x8 aPhi1 = *(const bf16x8*)(phi + lr * 128 + ((4 + lg) ^ rx) * 16);
      // --- PV: V^T frags from LDS serve both halves ---
      __builtin_amdgcn_s_setprio(1);
#pragma unroll
      for (int n2 = 0; n2 < 4; n2++) {
        bf16x8 v0 = *(const bf16x8*)&vl[(n2 * 16 + lr) * 64 + kc0];
        bf16x8 v1 = *(const bf16x8*)&vl[(n2 * 16 + lr) * 64 + kc1];
        Olo[n2] = __builtin_amdgcn_mfma_f32_16x16x32_bf16(aPlo0, v0, Olo[n2], 0, 0, 0);
        Olo[n2] = __builtin_amdgcn_mfma_f32_16x16x32_bf16(aPlo1, v1, Olo[n2], 0, 0, 0);
        Ohi[n2] = __builtin_amdgcn_mfma_f32_16x16x32_bf16(aPhi0, v0, Ohi[n2], 0, 0, 0);
        Ohi[n2] = __builtin_amdgcn_mfma_f32_16x16x32_bf16(aPhi1, v1, Ohi[n2], 0, 0, 0);
      }
      __builtin_amdgcn_s_setprio(0);
    }
    __syncthreads();  // drains prefetch vmcnt + protects LDS buffers
    cur ^= 1;
  }
  // --- epilogue ---
  float s0 = __shfl(sumlo, lband | g4);
  float s1 = __shfl(sumlo, lband | (g4 + 1));
  float s2 = __shfl(sumlo, lband | (g4 + 2));
  float s3 = __shfl(sumlo, lband | (g4 + 3));
  float t0 = __shfl(sumhi, lband | g4);
  float t1 = __shfl(sumhi, lband | (g4 + 1));
  float t2 = __shfl(sumhi, lband | (g4 + 2));
  float t3 = __shfl(sumhi, lband | (g4 + 3));
  float rl0 = 1.f / s0, rl1 = 1.f / s1, rl2 = 1.f / s2, rl3 = 1.f / s3;
  float rh0 = 1.f / t0, rh1 = 1.f / t1, rh2 = 1.f / t2, rh3 = 1.f / t3;
#pragma unroll
  for (int n2 = 0; n2 < 4; n2++) {
    size_t base = (size_t)(b * 2048 + q0 + g4) * 1024 + h * 64 + n2 * 16 + lr;
    y[base] = f2bf(Olo[n2][0] * rl0);
    y[base + 1024] = f2bf(Olo[n2][1] * rl1);
    y[base + 2048] = f2bf(Olo[n2][2] * rl2);
    y[base + 3072] = f2bf(Olo[n2][3] * rl3);
    size_t bhh = base + (size_t)16 * 1024;
    y[bhh] = f2bf(Ohi[n2][0] * rh0);
    y[bhh + 1024] = f2bf(Ohi[n2][1] * rh1);
    y[bhh + 2048] = f2bf(Ohi[n2][2] * rh2);
    y[bhh + 3072] = f2bf(Ohi[n2][3] * rh3);
  }
}

extern "C" void kernel_launch(void* const* d_in, const int* in_sizes, int n_in,
                              void* d_out, int out_size, void* d_ws, size_t ws_size,
                              hipStream_t stream) {
  const float* x = (const float*)d_in[0];
  const float* Wa = (const float*)d_in[1];
  const float* Wp = (const float*)d_in[2];
  float* out = (float*)d_out;

  char* ws = (char*)d_ws;
  size_t off = 0;
  unsigned short* xb = (unsigned short*)(ws + off);   off += (size_t)8192 * 1024 * 2;
  unsigned short* Wta = (unsigned short*)(ws + off);  off += (size_t)3072 * 1024 * 2;
  unsigned short* Wtp = (unsigned short*)(ws + off);  off += (size_t)1024 * 1024 * 2;
  unsigned short* qkvb = (unsigned short*)(ws + off); off += (size_t)8192 * 3072 * 2;
  unsigned short* vtb = (unsigned short*)(ws + off);  off += (size_t)64 * 64 * 2048 * 2;
  unsigned short* yb = (unsigned short*)(ws + off);   off += (size_t)8192 * 1024 * 2;

  f2bf_kernel<<<2048, 256, 0, stream>>>(x, xb, 8192 * 1024);
  transpose_f2bf<<<dim3(48, 16), 256, 0, stream>>>(Wa, Wta, 1024, 3072);
  transpose_f2bf<<<dim3(16, 16), 256, 0, stream>>>(Wp, Wtp, 1024, 1024);
  gemm_bt<unsigned short><<<dim3(24, 64), 256, 0, stream>>>(xb, Wta, qkvb, 8192, 3072, 1024);
  make_vt<<<dim3(64, 32), 256, 0, stream>>>(qkvb, vtb);
  attn_kernel<<<dim3(64, 16), 256, 0, stream>>>(qkvb, vtb, yb);
  gemm_bt<float><<<dim3(8, 64), 256, 0, stream>>>(yb, Wtp, out, 8192, 1024, 1024);
}

// Round 6
// 174.795 us; speedup vs baseline: 2.2083x; 1.0943x over previous
//
#include <hip/hip_runtime.h>
#include <stdint.h>

typedef __bf16 bf16x8 __attribute__((ext_vector_type(8)));
typedef float f32x4 __attribute__((ext_vector_type(4)));

__device__ __forceinline__ unsigned short f2bf(float f) {
  unsigned u = __builtin_bit_cast(unsigned, f);
  u = (u + 0x7fffu + ((u >> 16) & 1u)) >> 16;
  return (unsigned short)u;
}

__device__ __forceinline__ unsigned cvt_pk_bf16(float a, float b) {
  unsigned r;
  asm("v_cvt_pk_bf16_f32 %0, %1, %2" : "=v"(r) : "v"(a), "v"(b));
  return r;
}

__device__ __forceinline__ void gload_lds16(const unsigned short* g, unsigned short* l) {
  __builtin_amdgcn_global_load_lds(
      (__attribute__((address_space(1))) unsigned int*)g,
      (__attribute__((address_space(3))) unsigned int*)l, 16, 0, 0);
}

__device__ __forceinline__ void store_val(float* p, float v) { *p = v; }
__device__ __forceinline__ void store_val(unsigned short* p, float v) { *p = f2bf(v); }

// ---------------- fp32 -> bf16 convert ----------------
__global__ __launch_bounds__(256) void f2bf_kernel(const float* __restrict__ in,
                                                   unsigned short* __restrict__ out, int n) {
  int stride = gridDim.x * blockDim.x * 4;
  for (int i = (blockIdx.x * blockDim.x + threadIdx.x) * 4; i < n; i += stride) {
    float4 v = *(const float4*)(in + i);
    ushort4 o;
    o.x = f2bf(v.x); o.y = f2bf(v.y); o.z = f2bf(v.z); o.w = f2bf(v.w);
    *(ushort4*)(out + i) = o;
  }
}

// ---------------- transpose fp32 [R][C] -> bf16 [C][R] ----------------
__global__ __launch_bounds__(256) void transpose_f2bf(const float* __restrict__ in,
                                                      unsigned short* __restrict__ out,
                                                      int R, int Ccols) {
  __shared__ unsigned short t[64][65];
  int r0 = blockIdx.y * 64, c0 = blockIdx.x * 64;
  int tid = threadIdx.x;
#pragma unroll
  for (int rep = 0; rep < 16; rep++) {
    int idx = rep * 256 + tid;
    int rr = idx >> 6, cc = idx & 63;
    t[rr][cc] = f2bf(in[(size_t)(r0 + rr) * Ccols + c0 + cc]);
  }
  __syncthreads();
#pragma unroll
  for (int rep = 0; rep < 16; rep++) {
    int idx = rep * 256 + tid;
    int cc = idx >> 6, rr = idx & 63;
    out[(size_t)(c0 + cc) * R + r0 + rr] = t[rr][cc];
  }
}

// ---------------- build V^T per head: vt[bh][d][t] from qkv ----------------
__global__ __launch_bounds__(256) void make_vt(const unsigned short* __restrict__ qkv,
                                               unsigned short* __restrict__ vt) {
  __shared__ unsigned short t[64][65];
  int bh = blockIdx.x;
  int b = bh >> 4, h = bh & 15;
  int t0 = blockIdx.y * 64;
  int tid = threadIdx.x;
#pragma unroll
  for (int rep = 0; rep < 16; rep++) {
    int idx = rep * 256 + tid;
    int tt = idx >> 6, dd = idx & 63;
    t[tt][dd] = qkv[(size_t)(b * 2048 + t0 + tt) * 3072 + 2048 + h * 64 + dd];
  }
  __syncthreads();
#pragma unroll
  for (int rep = 0; rep < 16; rep++) {
    int idx = rep * 256 + tid;
    int dd = idx >> 6, tt = idx & 63;
    vt[(size_t)bh * 131072 + (size_t)dd * 2048 + t0 + tt] = t[tt][dd];
  }
}

// ---------------- bf16 GEMM: C[M][N] = A[M][K] * Bt[N][K]^T ----------------
// BM=128, BN=256, BK=64, 512 threads (8 waves, 2x4), per-wave 64x64 output.
// 3 LDS buffers, depth-2 prefetch, counted vmcnt(6) (T4), one barrier per
// K-tile. vmcnt discipline REQUIRES strictly tile-ordered issue (prologue:
// all 6 tile-0 loads, then all 6 tile-1 loads). 128B rows, chunk^(row&7)
// swizzle both sides. T1 XCD swizzle, m-fast tile order. T5 setprio.
template <typename OutT>
__global__ __launch_bounds__(512, 2) void gemm_bt(const unsigned short* __restrict__ A,
                                                  const unsigned short* __restrict__ Bt,
                                                  OutT* __restrict__ C, int M, int N, int K,
                                                  int mtiles) {
  __shared__ unsigned short lds3[3][24576];  // per buf: A 128x64 | B 256x64
  const int tid = threadIdx.x;
  const int wid = tid >> 6, l = tid & 63;
  const int wm = wid >> 2, wn = wid & 3;
  const int lr = l & 15, lg = l >> 4;

  int nwg = gridDim.x;
  int q8 = nwg >> 3;
  int bid = blockIdx.x;
  int bs = (bid & 7) * q8 + (bid >> 3);
  int mt = bs % mtiles, nt = bs / mtiles;
  const int m0 = mt * 128, n0 = nt * 256;

  const int srow = tid >> 3;
  const int schunk = ((tid & 7) ^ (srow & 7)) * 8;
  const unsigned short* gA0 = A + (size_t)(m0 + srow) * K + schunk;
  const unsigned short* gB0 = Bt + (size_t)(n0 + srow) * K + schunk;
  const int wslice = wid * 512;

  int arow[4], brow[2][2], xoff[2];
#pragma unroll
  for (int m = 0; m < 4; m++) arow[m] = (wm * 64 + m * 16 + lr) * 64;
#pragma unroll
  for (int qq = 0; qq < 2; qq++)
#pragma unroll
    for (int j = 0; j < 2; j++) brow[qq][j] = 8192 + (wn * 64 + qq * 32 + j * 16 + lr) * 64;
#pragma unroll
  for (int ks = 0; ks < 2; ks++) xoff[ks] = ((ks * 4 + lg) ^ (lr & 7)) * 8;

  f32x4 acc[4][4] = {};
  const int NT = K >> 6;

  // prologue: tile 0 fully, THEN tile 1 (issue order = tile order!)
  gload_lds16(gA0, &lds3[0][wslice]);
  gload_lds16(gA0 + (size_t)64 * K, &lds3[0][4096 + wslice]);
#pragma unroll
  for (int u = 0; u < 4; u++)
    gload_lds16(gB0 + (size_t)(u * 64) * K, &lds3[0][8192 + u * 4096 + wslice]);
  gload_lds16(gA0 + 64, &lds3[1][wslice]);
  gload_lds16(gA0 + (size_t)64 * K + 64, &lds3[1][4096 + wslice]);
#pragma unroll
  for (int u = 0; u < 4; u++)
    gload_lds16(gB0 + (size_t)(u * 64) * K + 64, &lds3[1][8192 + u * 4096 + wslice]);

  int cb = 0;
  for (int t = 0; t < NT; t++) {
    if (t == NT - 1) {
      asm volatile("s_waitcnt vmcnt(0)" ::: "memory");
    } else {
      asm volatile("s_waitcnt vmcnt(6)" ::: "memory");
    }
    __builtin_amdgcn_s_barrier();
    const unsigned short* bufc = lds3[cb];
    int pb = cb + 2; if (pb >= 3) pb -= 3;
    unsigned short* bufp = lds3[pb];
    const int k2 = (t + 2) * 64;
    const bool pre = (t + 2) < NT;

    // ---- phase 0: issue A0,A1,B0 of tile t+2; compute col-half 0 ----
    if (pre) {
      gload_lds16(gA0 + k2, bufp + wslice);
      gload_lds16(gA0 + (size_t)64 * K + k2, bufp + 4096 + wslice);
      gload_lds16(gB0 + k2, bufp + 8192 + wslice);
    }
    bf16x8 af[4][2];
#pragma unroll
    for (int m = 0; m < 4; m++)
#pragma unroll
      for (int ks = 0; ks < 2; ks++)
        af[m][ks] = *(const bf16x8*)&bufc[arow[m] + xoff[ks]];
    {
      bf16x8 bq[2][2];
#pragma unroll
      for (int j = 0; j < 2; j++)
#pragma unroll
        for (int ks = 0; ks < 2; ks++)
          bq[j][ks] = *(const bf16x8*)&bufc[brow[0][j] + xoff[ks]];
      __builtin_amdgcn_s_setprio(1);
#pragma unroll
      for (int m = 0; m < 4; m++)
#pragma unroll
        for (int j = 0; j < 2; j++)
#pragma unroll
          for (int ks = 0; ks < 2; ks++)
            acc[m][j] = __builtin_amdgcn_mfma_f32_16x16x32_bf16(af[m][ks], bq[j][ks], acc[m][j], 0, 0, 0);
      __builtin_amdgcn_s_setprio(0);
    }
    // ---- phase 1: issue B1,B2,B3 of tile t+2; compute col-half 1 ----
    if (pre) {
      gload_lds16(gB0 + (size_t)64 * K + k2, bufp + 12288 + wslice);
      gload_lds16(gB0 + (size_t)128 * K + k2, bufp + 16384 + wslice);
      gload_lds16(gB0 + (size_t)192 * K + k2, bufp + 20480 + wslice);
    }
    {
      bf16x8 bq[2][2];
#pragma unroll
      for (int j = 0; j < 2; j++)
#pragma unroll
        for (int ks = 0; ks < 2; ks++)
          bq[j][ks] = *(const bf16x8*)&bufc[brow[1][j] + xoff[ks]];
      __builtin_amdgcn_s_setprio(1);
#pragma unroll
      for (int m = 0; m < 4; m++)
#pragma unroll
        for (int j = 0; j < 2; j++)
#pragma unroll
          for (int ks = 0; ks < 2; ks++)
            acc[m][2 + j] = __builtin_amdgcn_mfma_f32_16x16x32_bf16(af[m][ks], bq[j][ks], acc[m][2 + j], 0, 0, 0);
      __builtin_amdgcn_s_setprio(0);
    }
    cb = (cb == 2) ? 0 : cb + 1;
  }

#pragma unroll
  for (int m = 0; m < 4; m++)
#pragma unroll
    for (int n = 0; n < 4; n++)
#pragma unroll
      for (int i = 0; i < 4; i++) {
        size_t row = (size_t)(m0 + wm * 64 + m * 16 + lg * 4 + i);
        size_t col = (size_t)(n0 + wn * 64 + n * 16 + lr);
        store_val(&C[row * N + col], acc[m][n][i]);
      }
}

// ---------------- flash attention, causal ----------------
__global__ __launch_bounds__(256, 2) void attn_kernel(const unsigned short* __restrict__ qkv,
                                                      const unsigned short* __restrict__ vt,
                                                      unsigned short* __restrict__ y) {
  __shared__ unsigned short k_lds[2][64 * 64];
  __shared__ unsigned short v_lds[2][64 * 64];
  __shared__ unsigned short p_lds[8][16 * 64];
  int tid = threadIdx.x;
  int w = tid >> 6, l = tid & 63;
  int lr = l & 15, lg = l >> 4;
  int g4 = lg * 4;
  int lband = l & 48;
  int bh = blockIdx.x;
  int b = bh >> 4, h = bh & 15;
  int qgrp = 15 - blockIdx.y;  // heavy-first
  int q0 = qgrp * 128 + w * 32;

  char* plo = (char*)p_lds[w * 2];
  char* phi = (char*)p_lds[w * 2 + 1];

  int srow = tid >> 3;
  int schunk = (tid & 7) ^ (srow & 7);
  const unsigned short* gK0 = qkv + (size_t)(b * 2048 + srow) * 3072 + 1024 + h * 64 + schunk * 8;
  const unsigned short* gK1 = gK0 + (size_t)32 * 3072;
  const unsigned short* gV0 = vt + (size_t)bh * 131072 + (size_t)srow * 2048 + schunk * 8;
  const unsigned short* gV1 = gV0 + (size_t)32 * 2048;
  int ldsbase0 = w * 512;
  int ldsbase1 = 2048 + w * 512;

  const unsigned short* qp = qkv + (size_t)(b * 2048 + q0 + lr) * 3072 + h * 64 + lg * 8;
  bf16x8 aQ0lo = *(const bf16x8*)qp;
  bf16x8 aQ1lo = *(const bf16x8*)(qp + 32);
  bf16x8 aQ0hi = *(const bf16x8*)(qp + 16 * 3072);
  bf16x8 aQ1hi = *(const bf16x8*)(qp + 16 * 3072 + 32);

  f32x4 Olo[4] = {}, Ohi[4] = {};
  float mlo = -3.0e38f, mhi = -3.0e38f;
  float sumlo = 0.f, sumhi = 0.f;
  const float SC = 0.125f * 1.44269504f;

  int rx = lr & 7;
  int kc0 = (lg ^ rx) * 8;
  int kc1 = ((4 + lg) ^ rx) * 8;

  int nbmax = ((qgrp * 128 + 96) >> 6) + 1;
  int kend = q0 + 31;
  int kdiag = q0 >> 6;

  gload_lds16(gK0, &k_lds[0][ldsbase0]);
  gload_lds16(gK1, &k_lds[0][ldsbase1]);
  gload_lds16(gV0, &v_lds[0][ldsbase0]);
  gload_lds16(gV1, &v_lds[0][ldsbase1]);
  __syncthreads();

  int cur = 0;
  for (int kb = 0; kb < nbmax; kb++) {
    int kbase = kb * 64;
    if (kb + 1 < nbmax) {
      size_t koff = (size_t)(kbase + 64) * 3072;
      size_t voff = (size_t)(kbase + 64);
      int nxt = cur ^ 1;
      gload_lds16(gK0 + koff, &k_lds[nxt][ldsbase0]);
      gload_lds16(gK1 + koff, &k_lds[nxt][ldsbase1]);
      gload_lds16(gV0 + voff, &v_lds[nxt][ldsbase0]);
      gload_lds16(gV1 + voff, &v_lds[nxt][ldsbase1]);
    }
    if (kbase <= kend) {
      const unsigned short* kl = k_lds[cur];
      const unsigned short* vl = v_lds[cur];
      f32x4 svlo[4], svhi[4];
      __builtin_amdgcn_s_setprio(1);
#pragma unroll
      for (int n = 0; n < 4; n++) {
        bf16x8 kf0 = *(const bf16x8*)&kl[(n * 16 + lr) * 64 + kc0];
        bf16x8 kf1 = *(const bf16x8*)&kl[(n * 16 + lr) * 64 + kc1];
        f32x4 z = {};
        z = __builtin_amdgcn_mfma_f32_16x16x32_bf16(kf0, aQ0lo, z, 0, 0, 0);
        z = __builtin_amdgcn_mfma_f32_16x16x32_bf16(kf1, aQ1lo, z, 0, 0, 0);
        svlo[n] = z;
        f32x4 z2 = {};
        z2 = __builtin_amdgcn_mfma_f32_16x16x32_bf16(kf0, aQ0hi, z2, 0, 0, 0);
        z2 = __builtin_amdgcn_mfma_f32_16x16x32_bf16(kf1, aQ1hi, z2, 0, 0, 0);
        svhi[n] = z2;
      }
      __builtin_amdgcn_s_setprio(0);
      float slo[4][4], shi[4][4];
#pragma unroll
      for (int n = 0; n < 4; n++)
#pragma unroll
        for (int i = 0; i < 4; i++) {
          slo[n][i] = svlo[n][i] * SC;
          shi[n][i] = svhi[n][i] * SC;
        }
      if (kb == kdiag) {
#pragma unroll
        for (int n = 0; n < 4; n++)
#pragma unroll
          for (int i = 0; i < 4; i++) {
            int kk = kbase + n * 16 + g4 + i;
            if (kk > q0 + lr) slo[n][i] = -1.0e38f;
            if (kk > q0 + 16 + lr) shi[n][i] = -1.0e38f;
          }
      }
      float tmlo = fmaxf(
          fmaxf(fmaxf(fmaxf(slo[0][0], slo[0][1]), fmaxf(slo[0][2], slo[0][3])),
                fmaxf(fmaxf(slo[1][0], slo[1][1]), fmaxf(slo[1][2], slo[1][3]))),
          fmaxf(fmaxf(fmaxf(slo[2][0], slo[2][1]), fmaxf(slo[2][2], slo[2][3])),
                fmaxf(fmaxf(slo[3][0], slo[3][1]), fmaxf(slo[3][2], slo[3][3]))));
      float tmhi = fmaxf(
          fmaxf(fmaxf(fmaxf(shi[0][0], shi[0][1]), fmaxf(shi[0][2], shi[0][3])),
                fmaxf(fmaxf(shi[1][0], shi[1][1]), fmaxf(shi[1][2], shi[1][3]))),
          fmaxf(fmaxf(fmaxf(shi[2][0], shi[2][1]), fmaxf(shi[2][2], shi[2][3])),
                fmaxf(fmaxf(shi[3][0], shi[3][1]), fmaxf(shi[3][2], shi[3][3]))));
      tmlo = fmaxf(tmlo, __shfl_xor(tmlo, 16));
      tmlo = fmaxf(tmlo, __shfl_xor(tmlo, 32));
      tmhi = fmaxf(tmhi, __shfl_xor(tmhi, 16));
      tmhi = fmaxf(tmhi, __shfl_xor(tmhi, 32));
      if (__any(tmlo > mlo + 11.54f || tmhi > mhi + 11.54f)) {
        float mnlo = fmaxf(mlo, tmlo), mnhi = fmaxf(mhi, tmhi);
        float faclo = __builtin_amdgcn_exp2f(mlo - mnlo);
        float fachi = __builtin_amdgcn_exp2f(mhi - mnhi);
        mlo = mnlo; mhi = mnhi;
        sumlo *= faclo; sumhi *= fachi;
        float f0 = __shfl(faclo, lband | g4);
        float f1 = __shfl(faclo, lband | (g4 + 1));
        float f2 = __shfl(faclo, lband | (g4 + 2));
        float f3 = __shfl(faclo, lband | (g4 + 3));
        float h0 = __shfl(fachi, lband | g4);
        float h1 = __shfl(fachi, lband | (g4 + 1));
        float h2 = __shfl(fachi, lband | (g4 + 2));
        float h3 = __shfl(fachi, lband | (g4 + 3));
#pragma unroll
        for (int n2 = 0; n2 < 4; n2++) {
          Olo[n2][0] *= f0; Olo[n2][1] *= f1; Olo[n2][2] *= f2; Olo[n2][3] *= f3;
          Ohi[n2][0] *= h0; Ohi[n2][1] *= h1; Ohi[n2][2] *= h2; Ohi[n2][3] *= h3;
        }
      }
      float pslo = 0.f, pshi = 0.f;
      unsigned pk0lo[4], pk1lo[4], pk0hi[4], pk1hi[4];
#pragma unroll
      for (int n = 0; n < 4; n++) {
        float a0 = __builtin_amdgcn_exp2f(slo[n][0] - mlo);
        float a1 = __builtin_amdgcn_exp2f(slo[n][1] - mlo);
        float a2 = __builtin_amdgcn_exp2f(slo[n][2] - mlo);
        float a3 = __builtin_amdgcn_exp2f(slo[n][3] - mlo);
        pslo += (a0 + a1) + (a2 + a3);
        pk0lo[n] = cvt_pk_bf16(a0, a1);
        pk1lo[n] = cvt_pk_bf16(a2, a3);
        float c0 = __builtin_amdgcn_exp2f(shi[n][0] - mhi);
        float c1 = __builtin_amdgcn_exp2f(shi[n][1] - mhi);
        float c2 = __builtin_amdgcn_exp2f(shi[n][2] - mhi);
        float c3 = __builtin_amdgcn_exp2f(shi[n][3] - mhi);
        pshi += (c0 + c1) + (c2 + c3);
        pk0hi[n] = cvt_pk_bf16(c0, c1);
        pk1hi[n] = cvt_pk_bf16(c2, c3);
      }
      pslo += __shfl_xor(pslo, 16);
      pslo += __shfl_xor(pslo, 32);
      pshi += __shfl_xor(pshi, 16);
      pshi += __shfl_xor(pshi, 32);
      sumlo += pslo;
      sumhi += pshi;
#pragma unroll
      for (int n = 0; n < 4; n++) {
        int chunk = (2 * n + (lg >> 1)) ^ (lr & 7);
        int off = lr * 128 + chunk * 16 + (lg & 1) * 8;
        *(uint2*)(plo + off) = make_uint2(pk0lo[n], pk1lo[n]);
        *(uint2*)(phi + off) = make_uint2(pk0hi[n], pk1hi[n]);
      }
      bf16x8 aPlo0 = *(const bf16x8*)(plo + lr * 128 + (lg ^ rx) * 16);
      bf16x8 aPlo1 = *(const bf16x8*)(plo + lr * 128 + ((4 + lg) ^ rx) * 16);
      bf16x8 aPhi0 = *(const bf16x8*)(phi + lr * 128 + (lg ^ rx) * 16);
      bf16x8 aPhi1 = *(const bf16x8*)(phi + lr * 128 + ((4 + lg) ^ rx) * 16);
      __builtin_amdgcn_s_setprio(1);
#pragma unroll
      for (int n2 = 0; n2 < 4; n2++) {
        bf16x8 v0 = *(const bf16x8*)&vl[(n2 * 16 + lr) * 64 + kc0];
        bf16x8 v1 = *(const bf16x8*)&vl[(n2 * 16 + lr) * 64 + kc1];
        Olo[n2] = __builtin_amdgcn_mfma_f32_16x16x32_bf16(aPlo0, v0, Olo[n2], 0, 0, 0);
        Olo[n2] = __builtin_amdgcn_mfma_f32_16x16x32_bf16(aPlo1, v1, Olo[n2], 0, 0, 0);
        Ohi[n2] = __builtin_amdgcn_mfma_f32_16x16x32_bf16(aPhi0, v0, Ohi[n2], 0, 0, 0);
        Ohi[n2] = __builtin_amdgcn_mfma_f32_16x16x32_bf16(aPhi1, v1, Ohi[n2], 0, 0, 0);
      }
      __builtin_amdgcn_s_setprio(0);
    }
    __syncthreads();
    cur ^= 1;
  }
  float s0 = __shfl(sumlo, lband | g4);
  float s1 = __shfl(sumlo, lband | (g4 + 1));
  float s2 = __shfl(sumlo, lband | (g4 + 2));
  float s3 = __shfl(sumlo, lband | (g4 + 3));
  float t0 = __shfl(sumhi, lband | g4);
  float t1 = __shfl(sumhi, lband | (g4 + 1));
  float t2 = __shfl(sumhi, lband | (g4 + 2));
  float t3 = __shfl(sumhi, lband | (g4 + 3));
  float rl0 = 1.f / s0, rl1 = 1.f / s1, rl2 = 1.f / s2, rl3 = 1.f / s3;
  float rh0 = 1.f / t0, rh1 = 1.f / t1, rh2 = 1.f / t2, rh3 = 1.f / t3;
#pragma unroll
  for (int n2 = 0; n2 < 4; n2++) {
    size_t base = (size_t)(b * 2048 + q0 + g4) * 1024 + h * 64 + n2 * 16 + lr;
    y[base] = f2bf(Olo[n2][0] * rl0);
    y[base + 1024] = f2bf(Olo[n2][1] * rl1);
    y[base + 2048] = f2bf(Olo[n2][2] * rl2);
    y[base + 3072] = f2bf(Olo[n2][3] * rl3);
    size_t bhh = base + (size_t)16 * 1024;
    y[bhh] = f2bf(Ohi[n2][0] * rh0);
    y[bhh + 1024] = f2bf(Ohi[n2][1] * rh1);
    y[bhh + 2048] = f2bf(Ohi[n2][2] * rh2);
    y[bhh + 3072] = f2bf(Ohi[n2][3] * rh3);
  }
}

extern "C" void kernel_launch(void* const* d_in, const int* in_sizes, int n_in,
                              void* d_out, int out_size, void* d_ws, size_t ws_size,
                              hipStream_t stream) {
  const float* x = (const float*)d_in[0];
  const float* Wa = (const float*)d_in[1];
  const float* Wp = (const float*)d_in[2];
  float* out = (float*)d_out;

  char* ws = (char*)d_ws;
  size_t off = 0;
  unsigned short* xb = (unsigned short*)(ws + off);   off += (size_t)8192 * 1024 * 2;
  unsigned short* Wta = (unsigned short*)(ws + off);  off += (size_t)3072 * 1024 * 2;
  unsigned short* Wtp = (unsigned short*)(ws + off);  off += (size_t)1024 * 1024 * 2;
  unsigned short* qkvb = (unsigned short*)(ws + off); off += (size_t)8192 * 3072 * 2;
  unsigned short* vtb = (unsigned short*)(ws + off);  off += (size_t)64 * 64 * 2048 * 2;
  unsigned short* yb = (unsigned short*)(ws + off);   off += (size_t)8192 * 1024 * 2;

  f2bf_kernel<<<2048, 256, 0, stream>>>(x, xb, 8192 * 1024);
  transpose_f2bf<<<dim3(48, 16), 256, 0, stream>>>(Wa, Wta, 1024, 3072);
  transpose_f2bf<<<dim3(16, 16), 256, 0, stream>>>(Wp, Wtp, 1024, 1024);
  gemm_bt<unsigned short><<<768, 512, 0, stream>>>(xb, Wta, qkvb, 8192, 3072, 1024, 64);
  make_vt<<<dim3(64, 32), 256, 0, stream>>>(qkvb, vtb);
  attn_kernel<<<dim3(64, 16), 256, 0, stream>>>(qkvb, vtb, yb);
  gemm_bt<float><<<256, 512, 0, stream>>>(yb, Wtp, out, 8192, 1024, 1024, 64);
}

// Round 8
// 172.848 us; speedup vs baseline: 2.2332x; 1.0113x over previous
//
#include <hip/hip_runtime.h>
#include <stdint.h>

typedef __bf16 bf16x8 __attribute__((ext_vector_type(8)));
typedef float f32x4 __attribute__((ext_vector_type(4)));

__device__ __forceinline__ unsigned short f2bf(float f) {
  unsigned u = __builtin_bit_cast(unsigned, f);
  u = (u + 0x7fffu + ((u >> 16) & 1u)) >> 16;
  return (unsigned short)u;
}

__device__ __forceinline__ unsigned cvt_pk_bf16(float a, float b) {
  unsigned r;
  asm("v_cvt_pk_bf16_f32 %0, %1, %2" : "=v"(r) : "v"(a), "v"(b));
  return r;
}

__device__ __forceinline__ void gload_lds16(const unsigned short* g, unsigned short* l) {
  __builtin_amdgcn_global_load_lds(
      (__attribute__((address_space(1))) unsigned int*)g,
      (__attribute__((address_space(3))) unsigned int*)l, 16, 0, 0);
}

__device__ __forceinline__ void store_val(float* p, float v) { *p = v; }
__device__ __forceinline__ void store_val(unsigned short* p, float v) { *p = f2bf(v); }

// ---------------- fp32 -> bf16 convert ----------------
__global__ __launch_bounds__(256) void f2bf_kernel(const float* __restrict__ in,
                                                   unsigned short* __restrict__ out, int n) {
  int stride = gridDim.x * blockDim.x * 4;
  for (int i = (blockIdx.x * blockDim.x + threadIdx.x) * 4; i < n; i += stride) {
    float4 v = *(const float4*)(in + i);
    ushort4 o;
    o.x = f2bf(v.x); o.y = f2bf(v.y); o.z = f2bf(v.z); o.w = f2bf(v.w);
    *(ushort4*)(out + i) = o;
  }
}

// ---------------- transpose fp32 [R][C] -> bf16 [C][R], optional col-scale ----
// Output feature (= input col) < qcols is multiplied by qscale (folds the
// attention scale*log2e into the Q weight columns for free).
__global__ __launch_bounds__(256) void transpose_f2bf(const float* __restrict__ in,
                                                      unsigned short* __restrict__ out,
                                                      int R, int Ccols, float qscale, int qcols) {
  __shared__ unsigned short t[64][65];
  int r0 = blockIdx.y * 64, c0 = blockIdx.x * 64;
  int tid = threadIdx.x;
#pragma unroll
  for (int rep = 0; rep < 16; rep++) {
    int idx = rep * 256 + tid;
    int rr = idx >> 6, cc = idx & 63;
    float v = in[(size_t)(r0 + rr) * Ccols + c0 + cc];
    if (c0 + cc < qcols) v *= qscale;
    t[rr][cc] = f2bf(v);
  }
  __syncthreads();
#pragma unroll
  for (int rep = 0; rep < 16; rep++) {
    int idx = rep * 256 + tid;
    int cc = idx >> 6, rr = idx & 63;
    out[(size_t)(c0 + cc) * R + r0 + rr] = t[rr][cc];
  }
}

// ---------------- build V^T per head: vt[bh][d][t] from qkv ----------------
__global__ __launch_bounds__(256) void make_vt(const unsigned short* __restrict__ qkv,
                                               unsigned short* __restrict__ vt) {
  __shared__ unsigned short t[64][65];
  int bh = blockIdx.x;
  int b = bh >> 4, h = bh & 15;
  int t0 = blockIdx.y * 64;
  int tid = threadIdx.x;
#pragma unroll
  for (int rep = 0; rep < 16; rep++) {
    int idx = rep * 256 + tid;
    int tt = idx >> 6, dd = idx & 63;
    t[tt][dd] = qkv[(size_t)(b * 2048 + t0 + tt) * 3072 + 2048 + h * 64 + dd];
  }
  __syncthreads();
#pragma unroll
  for (int rep = 0; rep < 16; rep++) {
    int idx = rep * 256 + tid;
    int dd = idx >> 6, tt = idx & 63;
    vt[(size_t)bh * 131072 + (size_t)dd * 2048 + t0 + tt] = t[tt][dd];
  }
}

// ---------------- bf16 GEMM: C[M][N] = A[M][K] * Bt[N][K]^T ----------------
// BM=128, BN=256, BK=64, 512 threads (8 waves, 2x4), per-wave 64x64 output.
// 3 LDS buffers, depth-2 prefetch, counted vmcnt(6) (T4), one barrier per
// K-tile. Issue order strictly tile-ordered. chunk^(row&7) swizzle both sides.
template <typename OutT>
__global__ __launch_bounds__(512, 2) void gemm_bt(const unsigned short* __restrict__ A,
                                                  const unsigned short* __restrict__ Bt,
                                                  OutT* __restrict__ C, int M, int N, int K,
                                                  int mtiles) {
  __shared__ unsigned short lds3[3][24576];  // per buf: A 128x64 | B 256x64
  const int tid = threadIdx.x;
  const int wid = tid >> 6, l = tid & 63;
  const int wm = wid >> 2, wn = wid & 3;
  const int lr = l & 15, lg = l >> 4;

  int nwg = gridDim.x;
  int q8 = nwg >> 3;
  int bid = blockIdx.x;
  int bs = (bid & 7) * q8 + (bid >> 3);
  int mt = bs % mtiles, nt = bs / mtiles;
  const int m0 = mt * 128, n0 = nt * 256;

  const int srow = tid >> 3;
  const int schunk = ((tid & 7) ^ (srow & 7)) * 8;
  const unsigned short* gA0 = A + (size_t)(m0 + srow) * K + schunk;
  const unsigned short* gB0 = Bt + (size_t)(n0 + srow) * K + schunk;
  const int wslice = wid * 512;

  int arow[4], brow[2][2], xoff[2];
#pragma unroll
  for (int m = 0; m < 4; m++) arow[m] = (wm * 64 + m * 16 + lr) * 64;
#pragma unroll
  for (int qq = 0; qq < 2; qq++)
#pragma unroll
    for (int j = 0; j < 2; j++) brow[qq][j] = 8192 + (wn * 64 + qq * 32 + j * 16 + lr) * 64;
#pragma unroll
  for (int ks = 0; ks < 2; ks++) xoff[ks] = ((ks * 4 + lg) ^ (lr & 7)) * 8;

  f32x4 acc[4][4] = {};
  const int NT = K >> 6;

  // prologue: tile 0 fully, THEN tile 1 (issue order = tile order!)
  gload_lds16(gA0, &lds3[0][wslice]);
  gload_lds16(gA0 + (size_t)64 * K, &lds3[0][4096 + wslice]);
#pragma unroll
  for (int u = 0; u < 4; u++)
    gload_lds16(gB0 + (size_t)(u * 64) * K, &lds3[0][8192 + u * 4096 + wslice]);
  gload_lds16(gA0 + 64, &lds3[1][wslice]);
  gload_lds16(gA0 + (size_t)64 * K + 64, &lds3[1][4096 + wslice]);
#pragma unroll
  for (int u = 0; u < 4; u++)
    gload_lds16(gB0 + (size_t)(u * 64) * K + 64, &lds3[1][8192 + u * 4096 + wslice]);

  int cb = 0;
  for (int t = 0; t < NT; t++) {
    if (t == NT - 1) {
      asm volatile("s_waitcnt vmcnt(0)" ::: "memory");
    } else {
      asm volatile("s_waitcnt vmcnt(6)" ::: "memory");
    }
    __builtin_amdgcn_s_barrier();
    const unsigned short* bufc = lds3[cb];
    int pb = cb + 2; if (pb >= 3) pb -= 3;
    unsigned short* bufp = lds3[pb];
    const int k2 = (t + 2) * 64;
    const bool pre = (t + 2) < NT;

    // ---- phase 0: issue A0,A1,B0 of tile t+2; compute col-half 0 ----
    if (pre) {
      gload_lds16(gA0 + k2, bufp + wslice);
      gload_lds16(gA0 + (size_t)64 * K + k2, bufp + 4096 + wslice);
      gload_lds16(gB0 + k2, bufp + 8192 + wslice);
    }
    bf16x8 af[4][2];
#pragma unroll
    for (int m = 0; m < 4; m++)
#pragma unroll
      for (int ks = 0; ks < 2; ks++)
        af[m][ks] = *(const bf16x8*)&bufc[arow[m] + xoff[ks]];
    {
      bf16x8 bq[2][2];
#pragma unroll
      for (int j = 0; j < 2; j++)
#pragma unroll
        for (int ks = 0; ks < 2; ks++)
          bq[j][ks] = *(const bf16x8*)&bufc[brow[0][j] + xoff[ks]];
      __builtin_amdgcn_s_setprio(1);
#pragma unroll
      for (int m = 0; m < 4; m++)
#pragma unroll
        for (int j = 0; j < 2; j++)
#pragma unroll
          for (int ks = 0; ks < 2; ks++)
            acc[m][j] = __builtin_amdgcn_mfma_f32_16x16x32_bf16(af[m][ks], bq[j][ks], acc[m][j], 0, 0, 0);
      __builtin_amdgcn_s_setprio(0);
    }
    // ---- phase 1: issue B1,B2,B3 of tile t+2; compute col-half 1 ----
    if (pre) {
      gload_lds16(gB0 + (size_t)64 * K + k2, bufp + 12288 + wslice);
      gload_lds16(gB0 + (size_t)128 * K + k2, bufp + 16384 + wslice);
      gload_lds16(gB0 + (size_t)192 * K + k2, bufp + 20480 + wslice);
    }
    {
      bf16x8 bq[2][2];
#pragma unroll
      for (int j = 0; j < 2; j++)
#pragma unroll
        for (int ks = 0; ks < 2; ks++)
          bq[j][ks] = *(const bf16x8*)&bufc[brow[1][j] + xoff[ks]];
      __builtin_amdgcn_s_setprio(1);
#pragma unroll
      for (int m = 0; m < 4; m++)
#pragma unroll
        for (int j = 0; j < 2; j++)
#pragma unroll
          for (int ks = 0; ks < 2; ks++)
            acc[m][2 + j] = __builtin_amdgcn_mfma_f32_16x16x32_bf16(af[m][ks], bq[j][ks], acc[m][2 + j], 0, 0, 0);
      __builtin_amdgcn_s_setprio(0);
    }
    cb = (cb == 2) ? 0 : cb + 1;
  }

#pragma unroll
  for (int m = 0; m < 4; m++)
#pragma unroll
    for (int n = 0; n < 4; n++)
#pragma unroll
      for (int i = 0; i < 4; i++) {
        size_t row = (size_t)(m0 + wm * 64 + m * 16 + lg * 4 + i);
        size_t col = (size_t)(n0 + wn * 64 + n * 16 + lr);
        store_val(&C[row * N + col], acc[m][n][i]);
      }
}

// ---------------- flash attention, causal ----------------
// Scores arrive pre-scaled (scale*log2e folded into Wq). Round-6-proven
// softmax (fp32 psum + shuffles). 3 blocks/CU.
__global__ __launch_bounds__(256, 3) void attn_kernel(const unsigned short* __restrict__ qkv,
                                                      const unsigned short* __restrict__ vt,
                                                      unsigned short* __restrict__ y) {
  __shared__ unsigned short k_lds[2][64 * 64];
  __shared__ unsigned short v_lds[2][64 * 64];
  __shared__ unsigned short p_lds[8][16 * 64];
  int tid = threadIdx.x;
  int w = tid >> 6, l = tid & 63;
  int lr = l & 15, lg = l >> 4;
  int g4 = lg * 4;
  int lband = l & 48;
  int bh = blockIdx.x;
  int b = bh >> 4, h = bh & 15;
  int qgrp = 15 - blockIdx.y;  // heavy-first
  int q0 = qgrp * 128 + w * 32;

  char* plo = (char*)p_lds[w * 2];
  char* phi = (char*)p_lds[w * 2 + 1];

  int srow = tid >> 3;
  int schunk = (tid & 7) ^ (srow & 7);
  const unsigned short* gK0 = qkv + (size_t)(b * 2048 + srow) * 3072 + 1024 + h * 64 + schunk * 8;
  const unsigned short* gK1 = gK0 + (size_t)32 * 3072;
  const unsigned short* gV0 = vt + (size_t)bh * 131072 + (size_t)srow * 2048 + schunk * 8;
  const unsigned short* gV1 = gV0 + (size_t)32 * 2048;
  int ldsbase0 = w * 512;
  int ldsbase1 = 2048 + w * 512;

  const unsigned short* qp = qkv + (size_t)(b * 2048 + q0 + lr) * 3072 + h * 64 + lg * 8;
  bf16x8 aQ0lo = *(const bf16x8*)qp;
  bf16x8 aQ1lo = *(const bf16x8*)(qp + 32);
  bf16x8 aQ0hi = *(const bf16x8*)(qp + 16 * 3072);
  bf16x8 aQ1hi = *(const bf16x8*)(qp + 16 * 3072 + 32);

  f32x4 Olo[4] = {}, Ohi[4] = {};
  float mlo = -3.0e38f, mhi = -3.0e38f;
  float sumlo = 0.f, sumhi = 0.f;

  int rx = lr & 7;
  int kc0 = (lg ^ rx) * 8;
  int kc1 = ((4 + lg) ^ rx) * 8;

  int nbmax = ((qgrp * 128 + 96) >> 6) + 1;
  int kend = q0 + 31;
  int kdiag = q0 >> 6;

  gload_lds16(gK0, &k_lds[0][ldsbase0]);
  gload_lds16(gK1, &k_lds[0][ldsbase1]);
  gload_lds16(gV0, &v_lds[0][ldsbase0]);
  gload_lds16(gV1, &v_lds[0][ldsbase1]);
  __syncthreads();

  int cur = 0;
  for (int kb = 0; kb < nbmax; kb++) {
    int kbase = kb * 64;
    if (kb + 1 < nbmax) {
      size_t koff = (size_t)(kbase + 64) * 3072;
      size_t voff = (size_t)(kbase + 64);
      int nxt = cur ^ 1;
      gload_lds16(gK0 + koff, &k_lds[nxt][ldsbase0]);
      gload_lds16(gK1 + koff, &k_lds[nxt][ldsbase1]);
      gload_lds16(gV0 + voff, &v_lds[nxt][ldsbase0]);
      gload_lds16(gV1 + voff, &v_lds[nxt][ldsbase1]);
    }
    if (kbase <= kend) {
      const unsigned short* kl = k_lds[cur];
      const unsigned short* vl = v_lds[cur];
      f32x4 svlo[4], svhi[4];
      __builtin_amdgcn_s_setprio(1);
#pragma unroll
      for (int n = 0; n < 4; n++) {
        bf16x8 kf0 = *(const bf16x8*)&kl[(n * 16 + lr) * 64 + kc0];
        bf16x8 kf1 = *(const bf16x8*)&kl[(n * 16 + lr) * 64 + kc1];
        f32x4 z = {};
        z = __builtin_amdgcn_mfma_f32_16x16x32_bf16(kf0, aQ0lo, z, 0, 0, 0);
        z = __builtin_amdgcn_mfma_f32_16x16x32_bf16(kf1, aQ1lo, z, 0, 0, 0);
        svlo[n] = z;
        f32x4 z2 = {};
        z2 = __builtin_amdgcn_mfma_f32_16x16x32_bf16(kf0, aQ0hi, z2, 0, 0, 0);
        z2 = __builtin_amdgcn_mfma_f32_16x16x32_bf16(kf1, aQ1hi, z2, 0, 0, 0);
        svhi[n] = z2;
      }
      __builtin_amdgcn_s_setprio(0);
      if (kb == kdiag) {  // wave-uniform: mask only the diagonal tile
#pragma unroll
        for (int n = 0; n < 4; n++)
#pragma unroll
          for (int i = 0; i < 4; i++) {
            int kk = kbase + n * 16 + g4 + i;
            if (kk > q0 + lr) svlo[n][i] = -1.0e38f;
            if (kk > q0 + 16 + lr) svhi[n][i] = -1.0e38f;
          }
      }
      float tmlo = fmaxf(
          fmaxf(fmaxf(fmaxf(svlo[0][0], svlo[0][1]), fmaxf(svlo[0][2], svlo[0][3])),
                fmaxf(fmaxf(svlo[1][0], svlo[1][1]), fmaxf(svlo[1][2], svlo[1][3]))),
          fmaxf(fmaxf(fmaxf(svlo[2][0], svlo[2][1]), fmaxf(svlo[2][2], svlo[2][3])),
                fmaxf(fmaxf(svlo[3][0], svlo[3][1]), fmaxf(svlo[3][2], svlo[3][3]))));
      float tmhi = fmaxf(
          fmaxf(fmaxf(fmaxf(svhi[0][0], svhi[0][1]), fmaxf(svhi[0][2], svhi[0][3])),
                fmaxf(fmaxf(svhi[1][0], svhi[1][1]), fmaxf(svhi[1][2], svhi[1][3]))),
          fmaxf(fmaxf(fmaxf(svhi[2][0], svhi[2][1]), fmaxf(svhi[2][2], svhi[2][3])),
                fmaxf(fmaxf(svhi[3][0], svhi[3][1]), fmaxf(svhi[3][2], svhi[3][3]))));
      tmlo = fmaxf(tmlo, __shfl_xor(tmlo, 16));
      tmlo = fmaxf(tmlo, __shfl_xor(tmlo, 32));
      tmhi = fmaxf(tmhi, __shfl_xor(tmhi, 16));
      tmhi = fmaxf(tmhi, __shfl_xor(tmhi, 32));
      if (__any(tmlo > mlo + 11.54f || tmhi > mhi + 11.54f)) {
        float mnlo = fmaxf(mlo, tmlo), mnhi = fmaxf(mhi, tmhi);
        float faclo = __builtin_amdgcn_exp2f(mlo - mnlo);
        float fachi = __builtin_amdgcn_exp2f(mhi - mnhi);
        mlo = mnlo; mhi = mnhi;
        sumlo *= faclo; sumhi *= fachi;
        float f0 = __shfl(faclo, lband | g4);
        float f1 = __shfl(faclo, lband | (g4 + 1));
        float f2 = __shfl(faclo, lband | (g4 + 2));
        float f3 = __shfl(faclo, lband | (g4 + 3));
        float h0 = __shfl(fachi, lband | g4);
        float h1 = __shfl(fachi, lband | (g4 + 1));
        float h2 = __shfl(fachi, lband | (g4 + 2));
        float h3 = __shfl(fachi, lband | (g4 + 3));
#pragma unroll
        for (int n2 = 0; n2 < 4; n2++) {
          Olo[n2][0] *= f0; Olo[n2][1] *= f1; Olo[n2][2] *= f2; Olo[n2][3] *= f3;
          Ohi[n2][0] *= h0; Ohi[n2][1] *= h1; Ohi[n2][2] *= h2; Ohi[n2][3] *= h3;
        }
      }
      float pslo = 0.f, pshi = 0.f;
      unsigned pk0lo[4], pk1lo[4], pk0hi[4], pk1hi[4];
#pragma unroll
      for (int n = 0; n < 4; n++) {
        float a0 = __builtin_amdgcn_exp2f(svlo[n][0] - mlo);
        float a1 = __builtin_amdgcn_exp2f(svlo[n][1] - mlo);
        float a2 = __builtin_amdgcn_exp2f(svlo[n][2] - mlo);
        float a3 = __builtin_amdgcn_exp2f(svlo[n][3] - mlo);
        pslo += (a0 + a1) + (a2 + a3);
        pk0lo[n] = cvt_pk_bf16(a0, a1);
        pk1lo[n] = cvt_pk_bf16(a2, a3);
        float c0 = __builtin_amdgcn_exp2f(svhi[n][0] - mhi);
        float c1 = __builtin_amdgcn_exp2f(svhi[n][1] - mhi);
        float c2 = __builtin_amdgcn_exp2f(svhi[n][2] - mhi);
        float c3 = __builtin_amdgcn_exp2f(svhi[n][3] - mhi);
        pshi += (c0 + c1) + (c2 + c3);
        pk0hi[n] = cvt_pk_bf16(c0, c1);
        pk1hi[n] = cvt_pk_bf16(c2, c3);
      }
      pslo += __shfl_xor(pslo, 16);
      pslo += __shfl_xor(pslo, 32);
      pshi += __shfl_xor(pshi, 16);
      pshi += __shfl_xor(pshi, 32);
      sumlo += pslo;
      sumhi += pshi;
#pragma unroll
      for (int n = 0; n < 4; n++) {
        int chunk = (2 * n + (lg >> 1)) ^ rx;
        int off = lr * 128 + chunk * 16 + (lg & 1) * 8;
        *(uint2*)(plo + off) = make_uint2(pk0lo[n], pk1lo[n]);
        *(uint2*)(phi + off) = make_uint2(pk0hi[n], pk1hi[n]);
      }
      bf16x8 aPlo0 = *(const bf16x8*)(plo + lr * 128 + (lg ^ rx) * 16);
      bf16x8 aPlo1 = *(const bf16x8*)(plo + lr * 128 + ((4 + lg) ^ rx) * 16);
      bf16x8 aPhi0 = *(const bf16x8*)(phi + lr * 128 + (lg ^ rx) * 16);
      bf16x8 aPhi1 = *(const bf16x8*)(phi + lr * 128 + ((4 + lg) ^ rx) * 16);
      __builtin_amdgcn_s_setprio(1);
#pragma unroll
      for (int n2 = 0; n2 < 4; n2++) {
        bf16x8 v0 = *(const bf16x8*)&vl[(n2 * 16 + lr) * 64 + kc0];
        bf16x8 v1 = *(const bf16x8*)&vl[(n2 * 16 + lr) * 64 + kc1];
        Olo[n2] = __builtin_amdgcn_mfma_f32_16x16x32_bf16(aPlo0, v0, Olo[n2], 0, 0, 0);
        Olo[n2] = __builtin_amdgcn_mfma_f32_16x16x32_bf16(aPlo1, v1, Olo[n2], 0, 0, 0);
        Ohi[n2] = __builtin_amdgcn_mfma_f32_16x16x32_bf16(aPhi0, v0, Ohi[n2], 0, 0, 0);
        Ohi[n2] = __builtin_amdgcn_mfma_f32_16x16x32_bf16(aPhi1, v1, Ohi[n2], 0, 0, 0);
      }
      __builtin_amdgcn_s_setprio(0);
    }
    __syncthreads();
    cur ^= 1;
  }
  float s0 = __shfl(sumlo, lband | g4);
  float s1 = __shfl(sumlo, lband | (g4 + 1));
  float s2 = __shfl(sumlo, lband | (g4 + 2));
  float s3 = __shfl(sumlo, lband | (g4 + 3));
  float t0 = __shfl(sumhi, lband | g4);
  float t1 = __shfl(sumhi, lband | (g4 + 1));
  float t2 = __shfl(sumhi, lband | (g4 + 2));
  float t3 = __shfl(sumhi, lband | (g4 + 3));
  float rl0 = 1.f / s0, rl1 = 1.f / s1, rl2 = 1.f / s2, rl3 = 1.f / s3;
  float rh0 = 1.f / t0, rh1 = 1.f / t1, rh2 = 1.f / t2, rh3 = 1.f / t3;
#pragma unroll
  for (int n2 = 0; n2 < 4; n2++) {
    size_t base = (size_t)(b * 2048 + q0 + g4) * 1024 + h * 64 + n2 * 16 + lr;
    y[base] = f2bf(Olo[n2][0] * rl0);
    y[base + 1024] = f2bf(Olo[n2][1] * rl1);
    y[base + 2048] = f2bf(Olo[n2][2] * rl2);
    y[base + 3072] = f2bf(Olo[n2][3] * rl3);
    size_t bhh = base + (size_t)16 * 1024;
    y[bhh] = f2bf(Ohi[n2][0] * rh0);
    y[bhh + 1024] = f2bf(Ohi[n2][1] * rh1);
    y[bhh + 2048] = f2bf(Ohi[n2][2] * rh2);
    y[bhh + 3072] = f2bf(Ohi[n2][3] * rh3);
  }
}

extern "C" void kernel_launch(void* const* d_in, const int* in_sizes, int n_in,
                              void* d_out, int out_size, void* d_ws, size_t ws_size,
                              hipStream_t stream) {
  const float* x = (const float*)d_in[0];
  const float* Wa = (const float*)d_in[1];
  const float* Wp = (const float*)d_in[2];
  float* out = (float*)d_out;

  char* ws = (char*)d_ws;
  size_t off = 0;
  unsigned short* xb = (unsigned short*)(ws + off);   off += (size_t)8192 * 1024 * 2;
  unsigned short* Wta = (unsigned short*)(ws + off);  off += (size_t)3072 * 1024 * 2;
  unsigned short* Wtp = (unsigned short*)(ws + off);  off += (size_t)1024 * 1024 * 2;
  unsigned short* qkvb = (unsigned short*)(ws + off); off += (size_t)8192 * 3072 * 2;
  unsigned short* vtb = (unsigned short*)(ws + off);  off += (size_t)64 * 64 * 2048 * 2;
  unsigned short* yb = (unsigned short*)(ws + off);   off += (size_t)8192 * 1024 * 2;

  const float SC = 0.125f * 1.44269504f;  // attn scale * log2(e), folded into Wq
  f2bf_kernel<<<2048, 256, 0, stream>>>(x, xb, 8192 * 1024);
  transpose_f2bf<<<dim3(48, 16), 256, 0, stream>>>(Wa, Wta, 1024, 3072, SC, 1024);
  transpose_f2bf<<<dim3(16, 16), 256, 0, stream>>>(Wp, Wtp, 1024, 1024, 1.0f, 0);
  gemm_bt<unsigned short><<<768, 512, 0, stream>>>(xb, Wta, qkvb, 8192, 3072, 1024, 64);
  make_vt<<<dim3(64, 32), 256, 0, stream>>>(qkvb, vtb);
  attn_kernel<<<dim3(64, 16), 256, 0, stream>>>(qkvb, vtb, yb);
  gemm_bt<float><<<256, 512, 0, stream>>>(yb, Wtp, out, 8192, 1024, 1024, 64);
}